// Round 1
// baseline (776.231 us; speedup 1.0000x reference)
//
#include <hip/hip_runtime.h>
#include <stdint.h>

typedef unsigned long long u64;
typedef unsigned int u32;

#define BB 4
#define NN 321408
#define K_PRE 1000
#define K_POST 300
#define CAP 4096
#define NW 16                 // 1000 bits -> 16 u64 words
#define NBIN 65536
#define SCORE_THR 0.05f
#define IOU_THR 0.5f

__device__ __forceinline__ float sigm(float x) { return 1.0f / (1.0f + expf(-x)); }

// ---------------- K1: score + key + histogram ----------------
__global__ void k_score(const float* __restrict__ cls, u32* __restrict__ key, u32* __restrict__ hist) {
    int t = blockIdx.x * 256 + threadIdx.x;      // grid = B*N/256 exactly (5022 blocks)
    const float* c = cls + (size_t)t * 3;
    float mx = fmaxf(c[0], fmaxf(c[1], c[2]));
    float s = sigm(mx);
    u32 k = 0;
    if (s >= SCORE_THR) k = __float_as_uint(s) | 0x80000000u;   // s>0 always -> monotone key
    key[t] = k;
    int b = t / NN;                               // wave never spans batches (N % 64 == 0)
    u32 bin = k >> 16;
    int lane = threadIdx.x & 63;
    u64 act = __ballot(k != 0);
    while (act) {
        int leader = __ffsll(act) - 1;
        u32 lbin = __shfl(bin, leader);
        u64 match = __ballot(k != 0 && bin == lbin);
        if (lane == leader) atomicAdd(&hist[b * NBIN + lbin], (u32)__popcll(match & act));
        act &= ~match;
    }
}

// ---------------- K2: find threshold bin per batch ----------------
__global__ void k_thresh(const u32* __restrict__ hist, u32* __restrict__ thr) {
    int b = blockIdx.x; int tid = threadIdx.x;   // 256 threads
    __shared__ u32 csum[256], cabove[256];
    __shared__ u32 s_target;
    const u32* h = hist + (size_t)b * NBIN;
    int base = tid * 256;
    u32 sum = 0;
    for (int j = 0; j < 256; ++j) sum += h[base + j];
    csum[tid] = sum;
    __syncthreads();
    if (tid == 0) {
        u32 acc = 0;
        for (int i = 255; i >= 0; --i) { cabove[i] = acc; acc += csum[i]; }
        s_target = (acc < K_PRE) ? acc : K_PRE;
        if (acc == 0) thr[b] = 0x10000u;          // no valid anchors: no candidates
    }
    __syncthreads();
    u32 target = s_target;
    if (target > 0) {
        u32 above = cabove[tid];
        if (above < target && above + csum[tid] >= target) {
            u32 acc = above;
            for (int j = 255; j >= 0; --j) {
                acc += h[base + j];
                if (acc >= target) { thr[b] = (u32)(base + j); break; }
            }
        }
    }
}

// ---------------- K3: compact candidates ----------------
__global__ void k_compact(const u32* __restrict__ key, const u32* __restrict__ thr,
                          u32* __restrict__ cnt, u64* __restrict__ cand) {
    int t = blockIdx.x * 256 + threadIdx.x;
    int b = t / NN;
    u32 n = (u32)(t - b * NN);
    u32 k = key[t];
    u32 T = thr[b];
    bool isc = (k != 0) && ((k >> 16) >= T);
    u64 bal = __ballot(isc);
    if (bal) {
        int lane = threadIdx.x & 63;
        int leader = __ffsll(bal) - 1;
        u32 basepos = 0;
        if (lane == leader) basepos = atomicAdd(&cnt[b], (u32)__popcll(bal));
        basepos = __shfl(basepos, leader);
        if (isc) {
            u32 off = basepos + (u32)__popcll(bal & ((1ull << lane) - 1ull));
            // ascending sort of ((~key)<<32)|idx == (score desc, idx asc) == jax top_k order
            if (off < CAP) cand[(size_t)b * CAP + off] = ((u64)(~k) << 32) | (u64)n;
        }
    }
}

// ---------------- K4: bitonic sort candidates, emit top-1000 indices ----------------
__global__ __launch_bounds__(1024) void k_sort(const u32* __restrict__ cnt, const u64* __restrict__ cand,
                                               u32* __restrict__ tki) {
    __shared__ u64 a[CAP];                        // 32 KB
    int b = blockIdx.x; int tid = threadIdx.x;
    u32 nc = cnt[b]; if (nc > CAP) nc = CAP;
    for (int i = tid; i < CAP; i += 1024) a[i] = (i < (int)nc) ? cand[(size_t)b * CAP + i] : ~0ull;
    for (u32 size = 2; size <= CAP; size <<= 1) {
        for (u32 stride = size >> 1; stride > 0; stride >>= 1) {
            __syncthreads();
            for (u32 t = tid; t < CAP / 2; t += 1024) {
                u32 lo = 2 * t - (t & (stride - 1));
                u32 hi = lo + stride;
                bool asc = ((lo & size) == 0);
                u64 x = a[lo], y = a[hi];
                bool sw = asc ? (x > y) : (x < y);
                if (sw) { a[lo] = y; a[hi] = x; }
            }
        }
    }
    __syncthreads();
    for (int i = tid; i < K_PRE; i += 1024) {
        u64 e = a[i];
        u32 kk = ~((u32)(e >> 32));
        tki[b * K_PRE + i] = (kk == 0) ? 0xFFFFFFFFu : (u32)e;
    }
}

// ---------------- K5: decode survivors ----------------
__global__ void k_decode(const float* __restrict__ boxp, const float* __restrict__ cls,
                         const float* __restrict__ dirp, const float* __restrict__ anch,
                         const u32* __restrict__ tki, float* __restrict__ tks, u32* __restrict__ meta,
                         float* __restrict__ box7, float* __restrict__ cor) {
    int t = blockIdx.x * 256 + threadIdx.x;
    if (t >= BB * K_PRE) return;
    int b = t / K_PRE;
    u32 idx = tki[t];
    float ob[7] = {0,0,0,0,0,0,0};
    float c5[5] = {0,0,0,0,0};
    float sc = 0.f; u32 mt = 0;
    if (idx != 0xFFFFFFFFu) {
        const float* A = anch + (size_t)idx * 7;
        const float* D = boxp + ((size_t)b * NN + idx) * 7;
        float xa=A[0], ya=A[1], za=A[2], wa=A[3], la=A[4], ha=A[5], ra=A[6];
        float xt=D[0], yt=D[1], zt=D[2], wt=D[3], lt=D[4], ht=D[5], rt=D[6];
        za = za + ha * 0.5f;
        float diag = sqrtf(la * la + wa * wa);
        float xg = xt * diag + xa;
        float yg = yt * diag + ya;
        float zg = zt * ha + za;
        float wg = expf(wt) * wa;
        float lg = expf(lt) * la;
        float hg = expf(ht) * ha;
        zg = zg - hg * 0.5f;
        float rg = rt + ra;
        ob[0]=xg; ob[1]=yg; ob[2]=zg; ob[3]=wg; ob[4]=lg; ob[5]=hg; ob[6]=rg;
        float cr = fabsf(cosf(rg)), sr = fabsf(sinf(rg));
        float hx = 0.5f * (wg * cr + lg * sr);
        float hy = 0.5f * (wg * sr + lg * cr);
        float x1 = xg - hx, x2 = xg + hx, y1 = yg - hy, y2 = yg + hy;
        c5[0]=x1; c5[1]=x2; c5[2]=y1; c5[3]=y2; c5[4]=(x2-x1)*(y2-y1);
        const float* cc = cls + ((size_t)b * NN + idx) * 3;
        float p0 = sigm(cc[0]), p1 = sigm(cc[1]), p2 = sigm(cc[2]);
        int lbl = 0; float best = p0;
        if (p1 > best) { best = p1; lbl = 1; }
        if (p2 > best) { best = p2; lbl = 2; }
        sc = best;
        const float* dd = dirp + ((size_t)b * NN + idx) * 2;
        int dl = (dd[1] > dd[0]) ? 1 : 0;
        mt = (u32)lbl | ((u32)dl << 8) | (1u << 16);
    }
    tks[t] = sc; meta[t] = mt;
    #pragma unroll
    for (int j = 0; j < 7; ++j) box7[(size_t)t * 7 + j] = ob[j];
    #pragma unroll
    for (int j = 0; j < 5; ++j) cor[(size_t)t * 5 + j] = c5[j];
}

// ---------------- K6: suppression bitmask matrix ----------------
__global__ void k_mask(const float* __restrict__ cor, u64* __restrict__ mask) {
    int t = blockIdx.x * 256 + threadIdx.x;       // B*K_PRE*NW = 64000
    if (t >= BB * K_PRE * NW) return;
    int w = t & (NW - 1);
    int rem = t >> 4;
    int i = rem % K_PRE;
    int b = rem / K_PRE;
    const float* R = cor + ((size_t)b * K_PRE + i) * 5;
    float x1 = R[0], x2 = R[1], y1 = R[2], y2 = R[3], ar = R[4];
    const float* CB = cor + (size_t)b * K_PRE * 5;
    u64 m = 0;
    int j0 = w * 64;
    for (int jj = 0; jj < 64; ++jj) {
        int j = j0 + jj;
        if (j <= i || j >= K_PRE) continue;
        const float* Cj = CB + (size_t)j * 5;
        float ix = fminf(x2, Cj[1]) - fmaxf(x1, Cj[0]); ix = fmaxf(ix, 0.f);
        float iy = fminf(y2, Cj[3]) - fmaxf(y1, Cj[2]); iy = fmaxf(iy, 0.f);
        float inter = ix * iy;
        float uni = ar + Cj[4] - inter;
        float iou = (uni > 0.f) ? inter / fmaxf(uni, 1e-12f) : 0.f;
        if (iou > IOU_THR) m |= (1ull << jj);
    }
    mask[((size_t)b * K_PRE + i) * NW + w] = m;
}

// ---------------- K7: greedy NMS (1 wave) + outputs ----------------
__global__ __launch_bounds__(256) void k_nms_out(const u32* __restrict__ meta, const float* __restrict__ box7,
                                                 const float* __restrict__ tks, const u64* __restrict__ mask,
                                                 float* __restrict__ out) {
    int b = blockIdx.x; int tid = threadIdx.x;
    __shared__ u64 keepw_s[NW];
    __shared__ int sel_s[K_POST];
    __shared__ int cnt_s;
    const u32* M = meta + b * K_PRE;
    int lane = tid & 63; int wv = tid >> 6;
    for (int base = 0; base < K_PRE; base += 256) {
        int slot = base + tid;
        bool v = (slot < K_PRE) && ((M[slot] >> 16) & 1u);
        u64 word = __ballot(v);
        if (lane == 0) keepw_s[(base >> 6) + wv] = word;
    }
    __syncthreads();
    if (tid < 64) {
        u64 kw = (lane < NW) ? keepw_s[lane] : 0ull;
        const u64* Mk = mask + (size_t)b * K_PRE * NW;
        u64 pf[16];
        #pragma unroll
        for (int j = 0; j < 16; ++j) pf[j] = (lane < NW) ? Mk[(size_t)j * NW + lane] : 0ull;
        int c = 0; bool done = false;
        for (int base = 0; base < K_PRE; base += 16) {
            if (done) break;
            #pragma unroll
            for (int jj = 0; jj < 16; ++jj) {
                int i = base + jj;
                u64 cur = pf[jj];
                int nf = i + 16;
                u64 nv = (lane < NW && nf < K_PRE) ? Mk[(size_t)nf * NW + lane] : 0ull;
                pf[jj] = nv;
                if (!done) {
                    int wi = i >> 6;
                    u64 row = __shfl(kw, wi);
                    if ((row >> (i & 63)) & 1ull) {
                        if (lane == 0) sel_s[c] = i;
                        ++c;
                        if (c == K_POST) { done = true; }
                        else if (lane < NW) kw &= ~cur;
                    }
                }
            }
        }
        if (lane == 0) cnt_s = c;
    }
    __syncthreads();
    int cnt = cnt_s;
    const float* BX = box7 + (size_t)b * K_PRE * 7;
    const float* SS = tks + b * K_PRE;
    for (int p = tid; p < K_POST; p += 256) {
        float ob[7] = {0,0,0,0,0,0,0};
        float sc = 0.f, lb = 0.f, vd = 0.f;
        if (p < cnt) {
            int i = sel_s[p];
            float xg = BX[i*7+0], yg = BX[i*7+1], zg = BX[i*7+2];
            bool in_range = (xg >= 0.0f) && (xg <= 69.12f) &&
                            (yg >= -39.68f) && (yg <= 39.68f) &&
                            (zg >= -5.0f) && (zg <= 5.0f);
            if (in_range) {
                u32 mt = M[i];
                int dl = (mt >> 8) & 0xFF;
                float r = BX[i*7+6];
                bool opp = ((r > 0.0f) != (dl == 1));
                float rf = r + (opp ? 3.14159274f : 0.0f);
                ob[0]=xg; ob[1]=yg; ob[2]=zg; ob[3]=BX[i*7+3]; ob[4]=BX[i*7+4]; ob[5]=BX[i*7+5]; ob[6]=rf;
                sc = SS[i]; lb = (float)(mt & 0xFF); vd = 1.0f;
            }
        }
        size_t ro = (size_t)(b * K_POST + p);
        #pragma unroll
        for (int j = 0; j < 7; ++j) out[ro * 7 + j] = ob[j];
        out[(size_t)BB * K_POST * 7 + ro] = lb;   // labels (as float values)
        out[(size_t)BB * K_POST * 8 + ro] = sc;   // scores
        out[(size_t)BB * K_POST * 9 + ro] = vd;   // valid (0/1)
    }
}

extern "C" void kernel_launch(void* const* d_in, const int* in_sizes, int n_in,
                              void* d_out, int out_size, void* d_ws, size_t ws_size,
                              hipStream_t stream) {
    const float* boxp = (const float*)d_in[0];
    const float* cls  = (const float*)d_in[1];
    const float* dirp = (const float*)d_in[2];
    const float* anch = (const float*)d_in[3];
    float* out = (float*)d_out;

    char* p = (char*)d_ws;
    u32* key  = (u32*)p; p += (size_t)BB * NN * 4;
    u32* hist = (u32*)p; p += (size_t)BB * NBIN * 4;
    u32* cnt  = (u32*)p; p += 256;
    u32* thr  = (u32*)p; p += 256;
    u64* cand = (u64*)p; p += (size_t)BB * CAP * 8;
    u32* tki  = (u32*)p; p += (size_t)BB * K_PRE * 4;
    float* tks = (float*)p; p += (size_t)BB * K_PRE * 4;
    u32* meta = (u32*)p; p += (size_t)BB * K_PRE * 4;
    float* box7 = (float*)p; p += (size_t)BB * K_PRE * 7 * 4;
    float* cor  = (float*)p; p += (size_t)BB * K_PRE * 5 * 4;
    u64* mask = (u64*)p; p += (size_t)BB * K_PRE * NW * 8;

    hipMemsetAsync(hist, 0, (size_t)BB * NBIN * 4, stream);
    hipMemsetAsync(cnt, 0, 256, stream);

    k_score<<<(BB * NN) / 256, 256, 0, stream>>>(cls, key, hist);
    k_thresh<<<BB, 256, 0, stream>>>(hist, thr);
    k_compact<<<(BB * NN) / 256, 256, 0, stream>>>(key, thr, cnt, cand);
    k_sort<<<BB, 1024, 0, stream>>>(cnt, cand, tki);
    k_decode<<<(BB * K_PRE + 255) / 256, 256, 0, stream>>>(boxp, cls, dirp, anch, tki, tks, meta, box7, cor);
    k_mask<<<(BB * K_PRE * NW + 255) / 256, 256, 0, stream>>>(cor, mask);
    k_nms_out<<<BB, 256, 0, stream>>>(meta, box7, tks, mask, out);
}

// Round 2
// 507.367 us; speedup vs baseline: 1.5299x; 1.5299x over previous
//
#include <hip/hip_runtime.h>
#include <stdint.h>

typedef unsigned long long u64;
typedef unsigned int u32;

#define BB 4
#define NN 321408
#define K_PRE 1000
#define K_POST 300
#define CAP 4096
#define NW 16                 // 1000 bits -> 16 u64 words
#define NBIN 65536
#define SCORE_THR 0.05f
#define IOU_THR 0.5f

__device__ __forceinline__ float sigm(float x) { return 1.0f / (1.0f + expf(-x)); }

// ---------------- K1: score + key + histogram ----------------
// Direct per-lane atomics: ~770 active bins/batch, ~400 adds/bin, striped
// across L2 channels -> negligible contention. (R0's wave-dedup loop ran ~60
// serial ballot iterations/wave: 3.4% VALUBusy, 536us. Don't aggregate.)
__global__ void k_score(const float* __restrict__ cls, u32* __restrict__ key, u32* __restrict__ hist) {
    int t = blockIdx.x * 256 + threadIdx.x;      // grid = B*N/256 exactly (5022 blocks)
    const float* c = cls + (size_t)t * 3;
    float mx = fmaxf(c[0], fmaxf(c[1], c[2]));
    float s = sigm(mx);
    u32 k = 0;
    if (s >= SCORE_THR) k = __float_as_uint(s) | 0x80000000u;   // s>0 always -> monotone key
    key[t] = k;
    int b = t / NN;                               // wave never spans batches (N % 64 == 0)
    if (k != 0) atomicAdd(&hist[b * NBIN + (k >> 16)], 1u);
}

// ---------------- K2: find threshold bin per batch ----------------
__global__ void k_thresh(const u32* __restrict__ hist, u32* __restrict__ thr) {
    int b = blockIdx.x; int tid = threadIdx.x;   // 256 threads
    __shared__ u32 csum[256], cabove[256];
    __shared__ u32 s_target;
    const u32* h = hist + (size_t)b * NBIN;
    int base = tid * 256;
    u32 sum = 0;
    for (int j = 0; j < 256; ++j) sum += h[base + j];
    csum[tid] = sum;
    __syncthreads();
    if (tid == 0) {
        u32 acc = 0;
        for (int i = 255; i >= 0; --i) { cabove[i] = acc; acc += csum[i]; }
        s_target = (acc < K_PRE) ? acc : K_PRE;
        if (acc == 0) thr[b] = 0x10000u;          // no valid anchors: no candidates
    }
    __syncthreads();
    u32 target = s_target;
    if (target > 0) {
        u32 above = cabove[tid];
        if (above < target && above + csum[tid] >= target) {
            u32 acc = above;
            for (int j = 255; j >= 0; --j) {
                acc += h[base + j];
                if (acc >= target) { thr[b] = (u32)(base + j); break; }
            }
        }
    }
}

// ---------------- K3: compact candidates ----------------
__global__ void k_compact(const u32* __restrict__ key, const u32* __restrict__ thr,
                          u32* __restrict__ cnt, u64* __restrict__ cand) {
    int t = blockIdx.x * 256 + threadIdx.x;
    int b = t / NN;
    u32 n = (u32)(t - b * NN);
    u32 k = key[t];
    u32 T = thr[b];
    bool isc = (k != 0) && ((k >> 16) >= T);
    u64 bal = __ballot(isc);
    if (bal) {
        int lane = threadIdx.x & 63;
        int leader = __ffsll(bal) - 1;
        u32 basepos = 0;
        if (lane == leader) basepos = atomicAdd(&cnt[b], (u32)__popcll(bal));
        basepos = __shfl(basepos, leader);
        if (isc) {
            u32 off = basepos + (u32)__popcll(bal & ((1ull << lane) - 1ull));
            // ascending sort of ((~key)<<32)|idx == (score desc, idx asc) == jax top_k order
            if (off < CAP) cand[(size_t)b * CAP + off] = ((u64)(~k) << 32) | (u64)n;
        }
    }
}

// ---------------- K4: bitonic sort candidates, emit top-1000 indices ----------------
__global__ __launch_bounds__(1024) void k_sort(const u32* __restrict__ cnt, const u64* __restrict__ cand,
                                               u32* __restrict__ tki) {
    __shared__ u64 a[CAP];                        // 32 KB
    int b = blockIdx.x; int tid = threadIdx.x;
    u32 nc = cnt[b]; if (nc > CAP) nc = CAP;
    for (int i = tid; i < CAP; i += 1024) a[i] = (i < (int)nc) ? cand[(size_t)b * CAP + i] : ~0ull;
    for (u32 size = 2; size <= CAP; size <<= 1) {
        for (u32 stride = size >> 1; stride > 0; stride >>= 1) {
            __syncthreads();
            for (u32 t = tid; t < CAP / 2; t += 1024) {
                u32 lo = 2 * t - (t & (stride - 1));
                u32 hi = lo + stride;
                bool asc = ((lo & size) == 0);
                u64 x = a[lo], y = a[hi];
                bool sw = asc ? (x > y) : (x < y);
                if (sw) { a[lo] = y; a[hi] = x; }
            }
        }
    }
    __syncthreads();
    for (int i = tid; i < K_PRE; i += 1024) {
        u64 e = a[i];
        u32 kk = ~((u32)(e >> 32));
        tki[b * K_PRE + i] = (kk == 0) ? 0xFFFFFFFFu : (u32)e;
    }
}

// ---------------- K5: decode survivors ----------------
__global__ void k_decode(const float* __restrict__ boxp, const float* __restrict__ cls,
                         const float* __restrict__ dirp, const float* __restrict__ anch,
                         const u32* __restrict__ tki, float* __restrict__ tks, u32* __restrict__ meta,
                         float* __restrict__ box7, float* __restrict__ cor) {
    int t = blockIdx.x * 256 + threadIdx.x;
    if (t >= BB * K_PRE) return;
    int b = t / K_PRE;
    u32 idx = tki[t];
    float ob[7] = {0,0,0,0,0,0,0};
    float c5[5] = {0,0,0,0,0};
    float sc = 0.f; u32 mt = 0;
    if (idx != 0xFFFFFFFFu) {
        const float* A = anch + (size_t)idx * 7;
        const float* D = boxp + ((size_t)b * NN + idx) * 7;
        float xa=A[0], ya=A[1], za=A[2], wa=A[3], la=A[4], ha=A[5], ra=A[6];
        float xt=D[0], yt=D[1], zt=D[2], wt=D[3], lt=D[4], ht=D[5], rt=D[6];
        za = za + ha * 0.5f;
        float diag = sqrtf(la * la + wa * wa);
        float xg = xt * diag + xa;
        float yg = yt * diag + ya;
        float zg = zt * ha + za;
        float wg = expf(wt) * wa;
        float lg = expf(lt) * la;
        float hg = expf(ht) * ha;
        zg = zg - hg * 0.5f;
        float rg = rt + ra;
        ob[0]=xg; ob[1]=yg; ob[2]=zg; ob[3]=wg; ob[4]=lg; ob[5]=hg; ob[6]=rg;
        float cr = fabsf(cosf(rg)), sr = fabsf(sinf(rg));
        float hx = 0.5f * (wg * cr + lg * sr);
        float hy = 0.5f * (wg * sr + lg * cr);
        float x1 = xg - hx, x2 = xg + hx, y1 = yg - hy, y2 = yg + hy;
        c5[0]=x1; c5[1]=x2; c5[2]=y1; c5[3]=y2; c5[4]=(x2-x1)*(y2-y1);
        const float* cc = cls + ((size_t)b * NN + idx) * 3;
        float p0 = sigm(cc[0]), p1 = sigm(cc[1]), p2 = sigm(cc[2]);
        int lbl = 0; float best = p0;
        if (p1 > best) { best = p1; lbl = 1; }
        if (p2 > best) { best = p2; lbl = 2; }
        sc = best;
        const float* dd = dirp + ((size_t)b * NN + idx) * 2;
        int dl = (dd[1] > dd[0]) ? 1 : 0;
        mt = (u32)lbl | ((u32)dl << 8) | (1u << 16);
    }
    tks[t] = sc; meta[t] = mt;
    #pragma unroll
    for (int j = 0; j < 7; ++j) box7[(size_t)t * 7 + j] = ob[j];
    #pragma unroll
    for (int j = 0; j < 5; ++j) cor[(size_t)t * 5 + j] = c5[j];
}

// ---------------- K6: suppression bitmask matrix ----------------
__global__ void k_mask(const float* __restrict__ cor, u64* __restrict__ mask) {
    int t = blockIdx.x * 256 + threadIdx.x;       // B*K_PRE*NW = 64000
    if (t >= BB * K_PRE * NW) return;
    int w = t & (NW - 1);
    int rem = t >> 4;
    int i = rem % K_PRE;
    int b = rem / K_PRE;
    const float* R = cor + ((size_t)b * K_PRE + i) * 5;
    float x1 = R[0], x2 = R[1], y1 = R[2], y2 = R[3], ar = R[4];
    const float* CB = cor + (size_t)b * K_PRE * 5;
    u64 m = 0;
    int j0 = w * 64;
    for (int jj = 0; jj < 64; ++jj) {
        int j = j0 + jj;
        if (j <= i || j >= K_PRE) continue;
        const float* Cj = CB + (size_t)j * 5;
        float ix = fminf(x2, Cj[1]) - fmaxf(x1, Cj[0]); ix = fmaxf(ix, 0.f);
        float iy = fminf(y2, Cj[3]) - fmaxf(y1, Cj[2]); iy = fmaxf(iy, 0.f);
        float inter = ix * iy;
        float uni = ar + Cj[4] - inter;
        float iou = (uni > 0.f) ? inter / fmaxf(uni, 1e-12f) : 0.f;
        if (iou > IOU_THR) m |= (1ull << jj);
    }
    mask[((size_t)b * K_PRE + i) * NW + w] = m;
}

// ---------------- K7: greedy NMS (1 wave) + outputs ----------------
__global__ __launch_bounds__(256) void k_nms_out(const u32* __restrict__ meta, const float* __restrict__ box7,
                                                 const float* __restrict__ tks, const u64* __restrict__ mask,
                                                 float* __restrict__ out) {
    int b = blockIdx.x; int tid = threadIdx.x;
    __shared__ u64 keepw_s[NW];
    __shared__ int sel_s[K_POST];
    __shared__ int cnt_s;
    const u32* M = meta + b * K_PRE;
    int lane = tid & 63; int wv = tid >> 6;
    for (int base = 0; base < K_PRE; base += 256) {
        int slot = base + tid;
        bool v = (slot < K_PRE) && ((M[slot] >> 16) & 1u);
        u64 word = __ballot(v);
        if (lane == 0) keepw_s[(base >> 6) + wv] = word;
    }
    __syncthreads();
    if (tid < 64) {
        u64 kw = (lane < NW) ? keepw_s[lane] : 0ull;
        const u64* Mk = mask + (size_t)b * K_PRE * NW;
        u64 pf[16];
        #pragma unroll
        for (int j = 0; j < 16; ++j) pf[j] = (lane < NW) ? Mk[(size_t)j * NW + lane] : 0ull;
        int c = 0; bool done = false;
        for (int base = 0; base < K_PRE; base += 16) {
            if (done) break;
            #pragma unroll
            for (int jj = 0; jj < 16; ++jj) {
                int i = base + jj;
                u64 cur = pf[jj];
                int nf = i + 16;
                u64 nv = (lane < NW && nf < K_PRE) ? Mk[(size_t)nf * NW + lane] : 0ull;
                pf[jj] = nv;
                if (!done) {
                    int wi = i >> 6;
                    u64 row = __shfl(kw, wi);
                    if ((row >> (i & 63)) & 1ull) {
                        if (lane == 0) sel_s[c] = i;
                        ++c;
                        if (c == K_POST) { done = true; }
                        else if (lane < NW) kw &= ~cur;
                    }
                }
            }
        }
        if (lane == 0) cnt_s = c;
    }
    __syncthreads();
    int cnt = cnt_s;
    const float* BX = box7 + (size_t)b * K_PRE * 7;
    const float* SS = tks + b * K_PRE;
    for (int p = tid; p < K_POST; p += 256) {
        float ob[7] = {0,0,0,0,0,0,0};
        float sc = 0.f, lb = 0.f, vd = 0.f;
        if (p < cnt) {
            int i = sel_s[p];
            float xg = BX[i*7+0], yg = BX[i*7+1], zg = BX[i*7+2];
            bool in_range = (xg >= 0.0f) && (xg <= 69.12f) &&
                            (yg >= -39.68f) && (yg <= 39.68f) &&
                            (zg >= -5.0f) && (zg <= 5.0f);
            if (in_range) {
                u32 mt = M[i];
                int dl = (mt >> 8) & 0xFF;
                float r = BX[i*7+6];
                bool opp = ((r > 0.0f) != (dl == 1));
                float rf = r + (opp ? 3.14159274f : 0.0f);
                ob[0]=xg; ob[1]=yg; ob[2]=zg; ob[3]=BX[i*7+3]; ob[4]=BX[i*7+4]; ob[5]=BX[i*7+5]; ob[6]=rf;
                sc = SS[i]; lb = (float)(mt & 0xFF); vd = 1.0f;
            }
        }
        size_t ro = (size_t)(b * K_POST + p);
        #pragma unroll
        for (int j = 0; j < 7; ++j) out[ro * 7 + j] = ob[j];
        out[(size_t)BB * K_POST * 7 + ro] = lb;   // labels (as float values)
        out[(size_t)BB * K_POST * 8 + ro] = sc;   // scores
        out[(size_t)BB * K_POST * 9 + ro] = vd;   // valid (0/1)
    }
}

extern "C" void kernel_launch(void* const* d_in, const int* in_sizes, int n_in,
                              void* d_out, int out_size, void* d_ws, size_t ws_size,
                              hipStream_t stream) {
    const float* boxp = (const float*)d_in[0];
    const float* cls  = (const float*)d_in[1];
    const float* dirp = (const float*)d_in[2];
    const float* anch = (const float*)d_in[3];
    float* out = (float*)d_out;

    char* p = (char*)d_ws;
    u32* key  = (u32*)p; p += (size_t)BB * NN * 4;
    u32* hist = (u32*)p; p += (size_t)BB * NBIN * 4;
    u32* cnt  = (u32*)p; p += 256;
    u32* thr  = (u32*)p; p += 256;
    u64* cand = (u64*)p; p += (size_t)BB * CAP * 8;
    u32* tki  = (u32*)p; p += (size_t)BB * K_PRE * 4;
    float* tks = (float*)p; p += (size_t)BB * K_PRE * 4;
    u32* meta = (u32*)p; p += (size_t)BB * K_PRE * 4;
    float* box7 = (float*)p; p += (size_t)BB * K_PRE * 7 * 4;
    float* cor  = (float*)p; p += (size_t)BB * K_PRE * 5 * 4;
    u64* mask = (u64*)p; p += (size_t)BB * K_PRE * NW * 8;

    hipMemsetAsync(hist, 0, (size_t)BB * NBIN * 4, stream);
    hipMemsetAsync(cnt, 0, 256, stream);

    k_score<<<(BB * NN) / 256, 256, 0, stream>>>(cls, key, hist);
    k_thresh<<<BB, 256, 0, stream>>>(hist, thr);
    k_compact<<<(BB * NN) / 256, 256, 0, stream>>>(key, thr, cnt, cand);
    k_sort<<<BB, 1024, 0, stream>>>(cnt, cand, tki);
    k_decode<<<(BB * K_PRE + 255) / 256, 256, 0, stream>>>(boxp, cls, dirp, anch, tki, tks, meta, box7, cor);
    k_mask<<<(BB * K_PRE * NW + 255) / 256, 256, 0, stream>>>(cor, mask);
    k_nms_out<<<BB, 256, 0, stream>>>(meta, box7, tks, mask, out);
}

// Round 3
// 398.685 us; speedup vs baseline: 1.9470x; 1.2726x over previous
//
#include <hip/hip_runtime.h>
#include <stdint.h>

typedef unsigned long long u64;
typedef unsigned int u32;

#define BB 4
#define NN 321408
#define K_PRE 1000
#define K_POST 300
#define CAP 4096
#define NW 16                 // 1000 bits -> 16 u64 words
#define SCORE_THR 0.05f
#define IOU_THR 0.5f
#define HB 252                // hist blocks per batch
#define CHUNK 1280            // anchors per hist block (256*5)

__device__ __forceinline__ float sigm(float x) { return 1.0f / (1.0f + expf(-x)); }

__device__ __forceinline__ u32 mkkey(float mx) {
    float s = sigm(mx);
    return (s >= SCORE_THR) ? (__float_as_uint(s) | 0x80000000u) : 0u;
}

// ---------------- K1: score -> sortable key (pure streaming, no atomics) ----------------
__global__ void k_score(const float* __restrict__ cls, u32* __restrict__ key) {
    int t = blockIdx.x * 256 + threadIdx.x;
    int a0 = t * 4;
    if (a0 >= BB * NN) return;
    const float4* c4 = (const float4*)(cls + (size_t)a0 * 3);
    float4 v0 = c4[0], v1 = c4[1], v2 = c4[2];
    uint4 o;
    o.x = mkkey(fmaxf(v0.x, fmaxf(v0.y, v0.z)));
    o.y = mkkey(fmaxf(v0.w, fmaxf(v1.x, v1.y)));
    o.z = mkkey(fmaxf(v1.z, fmaxf(v1.w, v2.x)));
    o.w = mkkey(fmaxf(v2.y, fmaxf(v2.z, v2.w)));
    *((uint4*)(key + a0)) = o;
}

// ---------------- K1b: coarse 256-bin histogram, LDS-aggregated, sliced output ----------------
__global__ void k_hist1(const u32* __restrict__ key, u32* __restrict__ bh) {
    __shared__ u32 h[256];
    int bb = blockIdx.x; int tid = threadIdx.x;   // grid = BB*HB
    int b = bb / HB, c = bb % HB;
    h[tid] = 0;
    __syncthreads();
    int start = c * CHUNK;
    int end = start + CHUNK; if (end > NN) end = NN;
    const u32* kb = key + (size_t)b * NN;
    for (int i = start + tid; i < end; i += 256) {
        u32 k = kb[i];
        if (k) atomicAdd(&h[k >> 24], 1u);        // LDS atomic: cheap
    }
    __syncthreads();
    bh[(size_t)bb * 256 + tid] = h[tid];           // coalesced, no global atomics
}

// ---------------- K2a: coarse threshold bin per batch ----------------
__global__ void k_thresh1(const u32* __restrict__ bh, u32* __restrict__ prm) {
    __shared__ u32 cs[256];
    int b = blockIdx.x, tid = threadIdx.x;        // grid=BB, block=256
    u32 s = 0;
    const u32* base = bh + (size_t)b * HB * 256;
    for (int c = 0; c < HB; ++c) s += base[c * 256 + tid];
    cs[tid] = s;
    __syncthreads();
    if (tid == 0) {
        u32 tot = 0;
        for (int i = 0; i < 256; ++i) tot += cs[i];
        u32 target = (tot < K_PRE) ? tot : K_PRE;
        u32 above = 0; u32 C = 255;
        if (target > 0) {
            u32 acc = 0;
            for (int i = 255; i >= 0; --i) {
                if (acc + cs[i] >= target) { C = (u32)i; above = acc; break; }
                acc += cs[i];
            }
        }
        prm[b * 4 + 0] = C; prm[b * 4 + 1] = target; prm[b * 4 + 2] = above;
    }
}

// ---------------- K2b: fine histogram inside coarse bin C (few-k atomics total) ----------------
__global__ void k_hist2(const u32* __restrict__ key, const u32* __restrict__ prm, u32* __restrict__ fine) {
    int bb = blockIdx.x, tid = threadIdx.x;       // grid = BB*HB
    int b = bb / HB, c = bb % HB;
    u32 C = prm[b * 4 + 0], target = prm[b * 4 + 1];
    if (target == 0) return;
    int start = c * CHUNK;
    int end = start + CHUNK; if (end > NN) end = NN;
    const u32* kb = key + (size_t)b * NN;
    for (int i = start + tid; i < end; i += 256) {
        u32 k = kb[i];
        if (k && (k >> 24) == C) atomicAdd(&fine[b * 256 + ((k >> 16) & 0xFF)], 1u);
    }
}

// ---------------- K2c: final 16-bit-bin threshold (same semantics as old k_thresh) ----------------
__global__ void k_thresh2(const u32* __restrict__ fine, const u32* __restrict__ prm, u32* __restrict__ thr) {
    __shared__ u32 fs[256];
    int b = blockIdx.x, tid = threadIdx.x;        // grid=BB, block=256
    fs[tid] = fine[b * 256 + tid];
    __syncthreads();
    if (tid == 0) {
        u32 C = prm[b * 4 + 0], target = prm[b * 4 + 1], above = prm[b * 4 + 2];
        if (target == 0) { thr[b] = 0x10000u; }
        else {
            u32 acc = above; u32 T = 0;
            for (int i = 255; i >= 0; --i) {
                acc += fs[i];
                if (acc >= target) { T = (u32)i; break; }
            }
            thr[b] = (C << 8) | T;
        }
    }
}

// ---------------- K3: compact candidates ----------------
__global__ void k_compact(const u32* __restrict__ key, const u32* __restrict__ thr,
                          u32* __restrict__ cnt, u64* __restrict__ cand) {
    int t = blockIdx.x * 256 + threadIdx.x;
    int b = t / NN;
    u32 n = (u32)(t - b * NN);
    u32 k = key[t];
    u32 T = thr[b];
    bool isc = (k != 0) && ((k >> 16) >= T);
    u64 bal = __ballot(isc);
    if (bal) {
        int lane = threadIdx.x & 63;
        int leader = __ffsll(bal) - 1;
        u32 basepos = 0;
        if (lane == leader) basepos = atomicAdd(&cnt[b], (u32)__popcll(bal));
        basepos = __shfl(basepos, leader);
        if (isc) {
            u32 off = basepos + (u32)__popcll(bal & ((1ull << lane) - 1ull));
            // ascending sort of ((~key)<<32)|idx == (score desc, idx asc) == jax top_k order
            if (off < CAP) cand[(size_t)b * CAP + off] = ((u64)(~k) << 32) | (u64)n;
        }
    }
}

// ---------------- K4: bitonic sort candidates, emit top-1000 indices ----------------
__global__ __launch_bounds__(1024) void k_sort(const u32* __restrict__ cnt, const u64* __restrict__ cand,
                                               u32* __restrict__ tki) {
    __shared__ u64 a[CAP];                        // 32 KB
    int b = blockIdx.x; int tid = threadIdx.x;
    u32 nc = cnt[b]; if (nc > CAP) nc = CAP;
    for (int i = tid; i < CAP; i += 1024) a[i] = (i < (int)nc) ? cand[(size_t)b * CAP + i] : ~0ull;
    for (u32 size = 2; size <= CAP; size <<= 1) {
        for (u32 stride = size >> 1; stride > 0; stride >>= 1) {
            __syncthreads();
            for (u32 t = tid; t < CAP / 2; t += 1024) {
                u32 lo = 2 * t - (t & (stride - 1));
                u32 hi = lo + stride;
                bool asc = ((lo & size) == 0);
                u64 x = a[lo], y = a[hi];
                bool sw = asc ? (x > y) : (x < y);
                if (sw) { a[lo] = y; a[hi] = x; }
            }
        }
    }
    __syncthreads();
    for (int i = tid; i < K_PRE; i += 1024) {
        u64 e = a[i];
        u32 kk = ~((u32)(e >> 32));
        tki[b * K_PRE + i] = (kk == 0) ? 0xFFFFFFFFu : (u32)e;
    }
}

// ---------------- K5: decode survivors ----------------
__global__ void k_decode(const float* __restrict__ boxp, const float* __restrict__ cls,
                         const float* __restrict__ dirp, const float* __restrict__ anch,
                         const u32* __restrict__ tki, float* __restrict__ tks, u32* __restrict__ meta,
                         float* __restrict__ box7, float* __restrict__ cor) {
    int t = blockIdx.x * 256 + threadIdx.x;
    if (t >= BB * K_PRE) return;
    int b = t / K_PRE;
    u32 idx = tki[t];
    float ob[7] = {0,0,0,0,0,0,0};
    float c5[5] = {0,0,0,0,0};
    float sc = 0.f; u32 mt = 0;
    if (idx != 0xFFFFFFFFu) {
        const float* A = anch + (size_t)idx * 7;
        const float* D = boxp + ((size_t)b * NN + idx) * 7;
        float xa=A[0], ya=A[1], za=A[2], wa=A[3], la=A[4], ha=A[5], ra=A[6];
        float xt=D[0], yt=D[1], zt=D[2], wt=D[3], lt=D[4], ht=D[5], rt=D[6];
        za = za + ha * 0.5f;
        float diag = sqrtf(la * la + wa * wa);
        float xg = xt * diag + xa;
        float yg = yt * diag + ya;
        float zg = zt * ha + za;
        float wg = expf(wt) * wa;
        float lg = expf(lt) * la;
        float hg = expf(ht) * ha;
        zg = zg - hg * 0.5f;
        float rg = rt + ra;
        ob[0]=xg; ob[1]=yg; ob[2]=zg; ob[3]=wg; ob[4]=lg; ob[5]=hg; ob[6]=rg;
        float cr = fabsf(cosf(rg)), sr = fabsf(sinf(rg));
        float hx = 0.5f * (wg * cr + lg * sr);
        float hy = 0.5f * (wg * sr + lg * cr);
        float x1 = xg - hx, x2 = xg + hx, y1 = yg - hy, y2 = yg + hy;
        c5[0]=x1; c5[1]=x2; c5[2]=y1; c5[3]=y2; c5[4]=(x2-x1)*(y2-y1);
        const float* cc = cls + ((size_t)b * NN + idx) * 3;
        float p0 = sigm(cc[0]), p1 = sigm(cc[1]), p2 = sigm(cc[2]);
        int lbl = 0; float best = p0;
        if (p1 > best) { best = p1; lbl = 1; }
        if (p2 > best) { best = p2; lbl = 2; }
        sc = best;
        const float* dd = dirp + ((size_t)b * NN + idx) * 2;
        int dl = (dd[1] > dd[0]) ? 1 : 0;
        mt = (u32)lbl | ((u32)dl << 8) | (1u << 16);
    }
    tks[t] = sc; meta[t] = mt;
    #pragma unroll
    for (int j = 0; j < 7; ++j) box7[(size_t)t * 7 + j] = ob[j];
    #pragma unroll
    for (int j = 0; j < 5; ++j) cor[(size_t)t * 5 + j] = c5[j];
}

// ---------------- K6: suppression bitmask matrix ----------------
__global__ void k_mask(const float* __restrict__ cor, u64* __restrict__ mask) {
    int t = blockIdx.x * 256 + threadIdx.x;       // B*K_PRE*NW = 64000
    if (t >= BB * K_PRE * NW) return;
    int w = t & (NW - 1);
    int rem = t >> 4;
    int i = rem % K_PRE;
    int b = rem / K_PRE;
    const float* R = cor + ((size_t)b * K_PRE + i) * 5;
    float x1 = R[0], x2 = R[1], y1 = R[2], y2 = R[3], ar = R[4];
    const float* CB = cor + (size_t)b * K_PRE * 5;
    u64 m = 0;
    int j0 = w * 64;
    for (int jj = 0; jj < 64; ++jj) {
        int j = j0 + jj;
        if (j <= i || j >= K_PRE) continue;
        const float* Cj = CB + (size_t)j * 5;
        float ix = fminf(x2, Cj[1]) - fmaxf(x1, Cj[0]); ix = fmaxf(ix, 0.f);
        float iy = fminf(y2, Cj[3]) - fmaxf(y1, Cj[2]); iy = fmaxf(iy, 0.f);
        float inter = ix * iy;
        float uni = ar + Cj[4] - inter;
        float iou = (uni > 0.f) ? inter / fmaxf(uni, 1e-12f) : 0.f;
        if (iou > IOU_THR) m |= (1ull << jj);
    }
    mask[((size_t)b * K_PRE + i) * NW + w] = m;
}

// ---------------- K7: greedy NMS (1 wave) + outputs ----------------
__global__ __launch_bounds__(256) void k_nms_out(const u32* __restrict__ meta, const float* __restrict__ box7,
                                                 const float* __restrict__ tks, const u64* __restrict__ mask,
                                                 float* __restrict__ out) {
    int b = blockIdx.x; int tid = threadIdx.x;
    __shared__ u64 keepw_s[NW];
    __shared__ int sel_s[K_POST];
    __shared__ int cnt_s;
    const u32* M = meta + b * K_PRE;
    int lane = tid & 63; int wv = tid >> 6;
    for (int base = 0; base < K_PRE; base += 256) {
        int slot = base + tid;
        bool v = (slot < K_PRE) && ((M[slot] >> 16) & 1u);
        u64 word = __ballot(v);
        if (lane == 0) keepw_s[(base >> 6) + wv] = word;
    }
    __syncthreads();
    if (tid < 64) {
        u64 kw = (lane < NW) ? keepw_s[lane] : 0ull;
        const u64* Mk = mask + (size_t)b * K_PRE * NW;
        u64 pf[16];
        #pragma unroll
        for (int j = 0; j < 16; ++j) pf[j] = (lane < NW) ? Mk[(size_t)j * NW + lane] : 0ull;
        int c = 0; bool done = false;
        for (int base = 0; base < K_PRE; base += 16) {
            if (done) break;
            #pragma unroll
            for (int jj = 0; jj < 16; ++jj) {
                int i = base + jj;
                u64 cur = pf[jj];
                int nf = i + 16;
                u64 nv = (lane < NW && nf < K_PRE) ? Mk[(size_t)nf * NW + lane] : 0ull;
                pf[jj] = nv;
                if (!done) {
                    int wi = i >> 6;
                    u64 row = __shfl(kw, wi);
                    if ((row >> (i & 63)) & 1ull) {
                        if (lane == 0) sel_s[c] = i;
                        ++c;
                        if (c == K_POST) { done = true; }
                        else if (lane < NW) kw &= ~cur;
                    }
                }
            }
        }
        if (lane == 0) cnt_s = c;
    }
    __syncthreads();
    int cnt = cnt_s;
    const float* BX = box7 + (size_t)b * K_PRE * 7;
    const float* SS = tks + b * K_PRE;
    for (int p = tid; p < K_POST; p += 256) {
        float ob[7] = {0,0,0,0,0,0,0};
        float sc = 0.f, lb = 0.f, vd = 0.f;
        if (p < cnt) {
            int i = sel_s[p];
            float xg = BX[i*7+0], yg = BX[i*7+1], zg = BX[i*7+2];
            bool in_range = (xg >= 0.0f) && (xg <= 69.12f) &&
                            (yg >= -39.68f) && (yg <= 39.68f) &&
                            (zg >= -5.0f) && (zg <= 5.0f);
            if (in_range) {
                u32 mt = M[i];
                int dl = (mt >> 8) & 0xFF;
                float r = BX[i*7+6];
                bool opp = ((r > 0.0f) != (dl == 1));
                float rf = r + (opp ? 3.14159274f : 0.0f);
                ob[0]=xg; ob[1]=yg; ob[2]=zg; ob[3]=BX[i*7+3]; ob[4]=BX[i*7+4]; ob[5]=BX[i*7+5]; ob[6]=rf;
                sc = SS[i]; lb = (float)(mt & 0xFF); vd = 1.0f;
            }
        }
        size_t ro = (size_t)(b * K_POST + p);
        #pragma unroll
        for (int j = 0; j < 7; ++j) out[ro * 7 + j] = ob[j];
        out[(size_t)BB * K_POST * 7 + ro] = lb;   // labels (as float values)
        out[(size_t)BB * K_POST * 8 + ro] = sc;   // scores
        out[(size_t)BB * K_POST * 9 + ro] = vd;   // valid (0/1)
    }
}

extern "C" void kernel_launch(void* const* d_in, const int* in_sizes, int n_in,
                              void* d_out, int out_size, void* d_ws, size_t ws_size,
                              hipStream_t stream) {
    const float* boxp = (const float*)d_in[0];
    const float* cls  = (const float*)d_in[1];
    const float* dirp = (const float*)d_in[2];
    const float* anch = (const float*)d_in[3];
    float* out = (float*)d_out;

    char* p = (char*)d_ws;
    u32* key  = (u32*)p; p += (size_t)BB * NN * 4;
    u32* bh   = (u32*)p; p += (size_t)BB * HB * 256 * 4;   // coarse hist slices, ~1MB
    u32* fine = (u32*)p; p += (size_t)BB * 256 * 4;
    u32* prm  = (u32*)p; p += 256;
    u32* cnt  = (u32*)p; p += 256;
    u32* thr  = (u32*)p; p += 256;
    u64* cand = (u64*)p; p += (size_t)BB * CAP * 8;
    u32* tki  = (u32*)p; p += (size_t)BB * K_PRE * 4;
    float* tks = (float*)p; p += (size_t)BB * K_PRE * 4;
    u32* meta = (u32*)p; p += (size_t)BB * K_PRE * 4;
    float* box7 = (float*)p; p += (size_t)BB * K_PRE * 7 * 4;
    float* cor  = (float*)p; p += (size_t)BB * K_PRE * 5 * 4;
    u64* mask = (u64*)p; p += (size_t)BB * K_PRE * NW * 8;

    hipMemsetAsync(fine, 0, (size_t)BB * 256 * 4, stream);
    hipMemsetAsync(cnt, 0, 256, stream);

    k_score<<<(BB * NN / 4 + 255) / 256, 256, 0, stream>>>(cls, key);
    k_hist1<<<BB * HB, 256, 0, stream>>>(key, bh);
    k_thresh1<<<BB, 256, 0, stream>>>(bh, prm);
    k_hist2<<<BB * HB, 256, 0, stream>>>(key, prm, fine);
    k_thresh2<<<BB, 256, 0, stream>>>(fine, prm, thr);
    k_compact<<<(BB * NN) / 256, 256, 0, stream>>>(key, thr, cnt, cand);
    k_sort<<<BB, 1024, 0, stream>>>(cnt, cand, tki);
    k_decode<<<(BB * K_PRE + 255) / 256, 256, 0, stream>>>(boxp, cls, dirp, anch, tki, tks, meta, box7, cor);
    k_mask<<<(BB * K_PRE * NW + 255) / 256, 256, 0, stream>>>(cor, mask);
    k_nms_out<<<BB, 256, 0, stream>>>(meta, box7, tks, mask, out);
}

// Round 4
// 274.903 us; speedup vs baseline: 2.8237x; 1.4503x over previous
//
#include <hip/hip_runtime.h>
#include <stdint.h>

typedef unsigned long long u64;
typedef unsigned int u32;

#define BB 4
#define NN 321408
#define K_PRE 1000
#define K_POST 300
#define CAP 4096
#define NW 16                 // 1000 bits -> 16 u64 words
#define SCORE_THR 0.05f
#define IOU_THR 0.5f
#define SB 314                // slice blocks per batch (ceil(NN/1024))
#define CH2 1024              // anchors per slice block

__device__ __forceinline__ float sigm(float x) { return 1.0f / (1.0f + expf(-x)); }

__device__ __forceinline__ u32 mkkey(float mx) {
    float s = sigm(mx);
    return (s >= SCORE_THR) ? (__float_as_uint(s) | 0x80000000u) : 0u;
}

// ---------------- K1: keys + coarse 256-bin LDS hist -> slices (no global atomics) ----------------
__global__ void k_score_hist(const float* __restrict__ cls, u32* __restrict__ key, u32* __restrict__ bh) {
    __shared__ u32 h[256];
    int bb = blockIdx.x, tid = threadIdx.x;       // grid = BB*SB
    int b = bb / SB, c = bb % SB;
    h[tid] = 0;
    __syncthreads();
    int a0 = c * CH2 + tid * 4;                   // NN % 4 == 0: full quads only
    if (a0 < NN) {
        const float4* c4 = (const float4*)(cls + ((size_t)b * NN + a0) * 3);
        float4 v0 = c4[0], v1 = c4[1], v2 = c4[2];
        uint4 o;
        o.x = mkkey(fmaxf(v0.x, fmaxf(v0.y, v0.z)));
        o.y = mkkey(fmaxf(v0.w, fmaxf(v1.x, v1.y)));
        o.z = mkkey(fmaxf(v1.z, fmaxf(v1.w, v2.x)));
        o.w = mkkey(fmaxf(v2.y, fmaxf(v2.z, v2.w)));
        *((uint4*)(key + (size_t)b * NN + a0)) = o;
        if (o.x) atomicAdd(&h[o.x >> 24], 1u);    // LDS atomics only
        if (o.y) atomicAdd(&h[o.y >> 24], 1u);
        if (o.z) atomicAdd(&h[o.z >> 24], 1u);
        if (o.w) atomicAdd(&h[o.w >> 24], 1u);
    }
    __syncthreads();
    bh[(size_t)bb * 256 + tid] = h[tid];          // coalesced slice write
}

// ---------------- K2a: coarse threshold bin per batch (reduce slices) ----------------
__global__ void k_thresh1(const u32* __restrict__ bh, u32* __restrict__ prm) {
    __shared__ u32 cs[256];
    int b = blockIdx.x, tid = threadIdx.x;        // grid=BB, block=256
    u32 s = 0;
    const u32* base = bh + (size_t)b * SB * 256;
    for (int c = 0; c < SB; ++c) s += base[c * 256 + tid];
    cs[tid] = s;
    __syncthreads();
    if (tid == 0) {
        u32 tot = 0;
        for (int i = 0; i < 256; ++i) tot += cs[i];
        u32 target = (tot < K_PRE) ? tot : K_PRE;
        u32 above = 0; u32 C = 255;
        if (target > 0) {
            u32 acc = 0;
            for (int i = 255; i >= 0; --i) {
                if (acc + cs[i] >= target) { C = (u32)i; above = acc; break; }
                acc += cs[i];
            }
        }
        prm[b * 4 + 0] = C; prm[b * 4 + 1] = target; prm[b * 4 + 2] = above;
    }
}

// ---------------- K2b: fine hist inside coarse bin C -> LDS + slices (no global atomics) ----------------
__global__ void k_hist2(const u32* __restrict__ key, const u32* __restrict__ prm, u32* __restrict__ bh2) {
    __shared__ u32 h[256];
    int bb = blockIdx.x, tid = threadIdx.x;       // grid = BB*SB
    int b = bb / SB, c = bb % SB;
    u32 C = prm[b * 4 + 0], target = prm[b * 4 + 1];
    h[tid] = 0;
    __syncthreads();
    int a0 = c * CH2 + tid * 4;
    if (target != 0 && a0 < NN) {
        uint4 kk = *((const uint4*)(key + (size_t)b * NN + a0));
        if ((kk.x >> 24) == C) atomicAdd(&h[(kk.x >> 16) & 0xFF], 1u);
        if ((kk.y >> 24) == C) atomicAdd(&h[(kk.y >> 16) & 0xFF], 1u);
        if ((kk.z >> 24) == C) atomicAdd(&h[(kk.z >> 16) & 0xFF], 1u);
        if ((kk.w >> 24) == C) atomicAdd(&h[(kk.w >> 16) & 0xFF], 1u);
    }
    __syncthreads();
    bh2[(size_t)bb * 256 + tid] = h[tid];
}

// ---------------- K2c: final 16-bit-bin threshold (reduce slices; same semantics as R1 k_thresh) ----------------
__global__ void k_thresh2(const u32* __restrict__ bh2, const u32* __restrict__ prm, u32* __restrict__ thr) {
    __shared__ u32 fs[256];
    int b = blockIdx.x, tid = threadIdx.x;        // grid=BB, block=256
    u32 s = 0;
    const u32* base = bh2 + (size_t)b * SB * 256;
    for (int c = 0; c < SB; ++c) s += base[c * 256 + tid];
    fs[tid] = s;
    __syncthreads();
    if (tid == 0) {
        u32 C = prm[b * 4 + 0], target = prm[b * 4 + 1], above = prm[b * 4 + 2];
        if (target == 0) { thr[b] = 0x10000u; }
        else {
            u32 acc = above; u32 T = 0;
            for (int i = 255; i >= 0; --i) {
                acc += fs[i];
                if (acc >= target) { T = (u32)i; break; }
            }
            thr[b] = (C << 8) | T;
        }
    }
}

// ---------------- K3: compact candidates ----------------
__global__ void k_compact(const u32* __restrict__ key, const u32* __restrict__ thr,
                          u32* __restrict__ cnt, u64* __restrict__ cand) {
    int t = blockIdx.x * 256 + threadIdx.x;
    int b = t / NN;
    u32 n = (u32)(t - b * NN);
    u32 k = key[t];
    u32 T = thr[b];
    bool isc = (k != 0) && ((k >> 16) >= T);
    u64 bal = __ballot(isc);
    if (bal) {
        int lane = threadIdx.x & 63;
        int leader = __ffsll(bal) - 1;
        u32 basepos = 0;
        if (lane == leader) basepos = atomicAdd(&cnt[b], (u32)__popcll(bal));
        basepos = __shfl(basepos, leader);
        if (isc) {
            u32 off = basepos + (u32)__popcll(bal & ((1ull << lane) - 1ull));
            // ascending sort of ((~key)<<32)|idx == (score desc, idx asc) == jax top_k order
            if (off < CAP) cand[(size_t)b * CAP + off] = ((u64)(~k) << 32) | (u64)n;
        }
    }
}

// ---------------- K4: bitonic sort candidates, emit top-1000 indices ----------------
__global__ __launch_bounds__(1024) void k_sort(const u32* __restrict__ cnt, const u64* __restrict__ cand,
                                               u32* __restrict__ tki) {
    __shared__ u64 a[CAP];                        // 32 KB
    int b = blockIdx.x; int tid = threadIdx.x;
    u32 nc = cnt[b]; if (nc > CAP) nc = CAP;
    for (int i = tid; i < CAP; i += 1024) a[i] = (i < (int)nc) ? cand[(size_t)b * CAP + i] : ~0ull;
    for (u32 size = 2; size <= CAP; size <<= 1) {
        for (u32 stride = size >> 1; stride > 0; stride >>= 1) {
            __syncthreads();
            for (u32 t = tid; t < CAP / 2; t += 1024) {
                u32 lo = 2 * t - (t & (stride - 1));
                u32 hi = lo + stride;
                bool asc = ((lo & size) == 0);
                u64 x = a[lo], y = a[hi];
                bool sw = asc ? (x > y) : (x < y);
                if (sw) { a[lo] = y; a[hi] = x; }
            }
        }
    }
    __syncthreads();
    for (int i = tid; i < K_PRE; i += 1024) {
        u64 e = a[i];
        u32 kk = ~((u32)(e >> 32));
        tki[b * K_PRE + i] = (kk == 0) ? 0xFFFFFFFFu : (u32)e;
    }
}

// ---------------- K5: decode survivors ----------------
__global__ void k_decode(const float* __restrict__ boxp, const float* __restrict__ cls,
                         const float* __restrict__ dirp, const float* __restrict__ anch,
                         const u32* __restrict__ tki, float* __restrict__ tks, u32* __restrict__ meta,
                         float* __restrict__ box7, float* __restrict__ cor) {
    int t = blockIdx.x * 256 + threadIdx.x;
    if (t >= BB * K_PRE) return;
    int b = t / K_PRE;
    u32 idx = tki[t];
    float ob[7] = {0,0,0,0,0,0,0};
    float c5[5] = {0,0,0,0,0};
    float sc = 0.f; u32 mt = 0;
    if (idx != 0xFFFFFFFFu) {
        const float* A = anch + (size_t)idx * 7;
        const float* D = boxp + ((size_t)b * NN + idx) * 7;
        float xa=A[0], ya=A[1], za=A[2], wa=A[3], la=A[4], ha=A[5], ra=A[6];
        float xt=D[0], yt=D[1], zt=D[2], wt=D[3], lt=D[4], ht=D[5], rt=D[6];
        za = za + ha * 0.5f;
        float diag = sqrtf(la * la + wa * wa);
        float xg = xt * diag + xa;
        float yg = yt * diag + ya;
        float zg = zt * ha + za;
        float wg = expf(wt) * wa;
        float lg = expf(lt) * la;
        float hg = expf(ht) * ha;
        zg = zg - hg * 0.5f;
        float rg = rt + ra;
        ob[0]=xg; ob[1]=yg; ob[2]=zg; ob[3]=wg; ob[4]=lg; ob[5]=hg; ob[6]=rg;
        float cr = fabsf(cosf(rg)), sr = fabsf(sinf(rg));
        float hx = 0.5f * (wg * cr + lg * sr);
        float hy = 0.5f * (wg * sr + lg * cr);
        float x1 = xg - hx, x2 = xg + hx, y1 = yg - hy, y2 = yg + hy;
        c5[0]=x1; c5[1]=x2; c5[2]=y1; c5[3]=y2; c5[4]=(x2-x1)*(y2-y1);
        const float* cc = cls + ((size_t)b * NN + idx) * 3;
        float p0 = sigm(cc[0]), p1 = sigm(cc[1]), p2 = sigm(cc[2]);
        int lbl = 0; float best = p0;
        if (p1 > best) { best = p1; lbl = 1; }
        if (p2 > best) { best = p2; lbl = 2; }
        sc = best;
        const float* dd = dirp + ((size_t)b * NN + idx) * 2;
        int dl = (dd[1] > dd[0]) ? 1 : 0;
        mt = (u32)lbl | ((u32)dl << 8) | (1u << 16);
    }
    tks[t] = sc; meta[t] = mt;
    #pragma unroll
    for (int j = 0; j < 7; ++j) box7[(size_t)t * 7 + j] = ob[j];
    #pragma unroll
    for (int j = 0; j < 5; ++j) cor[(size_t)t * 5 + j] = c5[j];
}

// ---------------- K6: suppression bitmask matrix ----------------
__global__ void k_mask(const float* __restrict__ cor, u64* __restrict__ mask) {
    int t = blockIdx.x * 256 + threadIdx.x;       // B*K_PRE*NW = 64000
    if (t >= BB * K_PRE * NW) return;
    int w = t & (NW - 1);
    int rem = t >> 4;
    int i = rem % K_PRE;
    int b = rem / K_PRE;
    const float* R = cor + ((size_t)b * K_PRE + i) * 5;
    float x1 = R[0], x2 = R[1], y1 = R[2], y2 = R[3], ar = R[4];
    const float* CB = cor + (size_t)b * K_PRE * 5;
    u64 m = 0;
    int j0 = w * 64;
    for (int jj = 0; jj < 64; ++jj) {
        int j = j0 + jj;
        if (j <= i || j >= K_PRE) continue;
        const float* Cj = CB + (size_t)j * 5;
        float ix = fminf(x2, Cj[1]) - fmaxf(x1, Cj[0]); ix = fmaxf(ix, 0.f);
        float iy = fminf(y2, Cj[3]) - fmaxf(y1, Cj[2]); iy = fmaxf(iy, 0.f);
        float inter = ix * iy;
        float uni = ar + Cj[4] - inter;
        float iou = (uni > 0.f) ? inter / fmaxf(uni, 1e-12f) : 0.f;
        if (iou > IOU_THR) m |= (1ull << jj);
    }
    mask[((size_t)b * K_PRE + i) * NW + w] = m;
}

// ---------------- K7: greedy NMS (1 wave) + outputs ----------------
__global__ __launch_bounds__(256) void k_nms_out(const u32* __restrict__ meta, const float* __restrict__ box7,
                                                 const float* __restrict__ tks, const u64* __restrict__ mask,
                                                 float* __restrict__ out) {
    int b = blockIdx.x; int tid = threadIdx.x;
    __shared__ u64 keepw_s[NW];
    __shared__ int sel_s[K_POST];
    __shared__ int cnt_s;
    const u32* M = meta + b * K_PRE;
    int lane = tid & 63; int wv = tid >> 6;
    for (int base = 0; base < K_PRE; base += 256) {
        int slot = base + tid;
        bool v = (slot < K_PRE) && ((M[slot] >> 16) & 1u);
        u64 word = __ballot(v);
        if (lane == 0) keepw_s[(base >> 6) + wv] = word;
    }
    __syncthreads();
    if (tid < 64) {
        u64 kw = (lane < NW) ? keepw_s[lane] : 0ull;
        const u64* Mk = mask + (size_t)b * K_PRE * NW;
        u64 pf[16];
        #pragma unroll
        for (int j = 0; j < 16; ++j) pf[j] = (lane < NW) ? Mk[(size_t)j * NW + lane] : 0ull;
        int c = 0; bool done = false;
        for (int base = 0; base < K_PRE; base += 16) {
            if (done) break;
            #pragma unroll
            for (int jj = 0; jj < 16; ++jj) {
                int i = base + jj;
                u64 cur = pf[jj];
                int nf = i + 16;
                u64 nv = (lane < NW && nf < K_PRE) ? Mk[(size_t)nf * NW + lane] : 0ull;
                pf[jj] = nv;
                if (!done) {
                    int wi = i >> 6;
                    u64 row = __shfl(kw, wi);
                    if ((row >> (i & 63)) & 1ull) {
                        if (lane == 0) sel_s[c] = i;
                        ++c;
                        if (c == K_POST) { done = true; }
                        else if (lane < NW) kw &= ~cur;
                    }
                }
            }
        }
        if (lane == 0) cnt_s = c;
    }
    __syncthreads();
    int cnt = cnt_s;
    const float* BX = box7 + (size_t)b * K_PRE * 7;
    const float* SS = tks + b * K_PRE;
    for (int p = tid; p < K_POST; p += 256) {
        float ob[7] = {0,0,0,0,0,0,0};
        float sc = 0.f, lb = 0.f, vd = 0.f;
        if (p < cnt) {
            int i = sel_s[p];
            float xg = BX[i*7+0], yg = BX[i*7+1], zg = BX[i*7+2];
            bool in_range = (xg >= 0.0f) && (xg <= 69.12f) &&
                            (yg >= -39.68f) && (yg <= 39.68f) &&
                            (zg >= -5.0f) && (zg <= 5.0f);
            if (in_range) {
                u32 mt = M[i];
                int dl = (mt >> 8) & 0xFF;
                float r = BX[i*7+6];
                bool opp = ((r > 0.0f) != (dl == 1));
                float rf = r + (opp ? 3.14159274f : 0.0f);
                ob[0]=xg; ob[1]=yg; ob[2]=zg; ob[3]=BX[i*7+3]; ob[4]=BX[i*7+4]; ob[5]=BX[i*7+5]; ob[6]=rf;
                sc = SS[i]; lb = (float)(mt & 0xFF); vd = 1.0f;
            }
        }
        size_t ro = (size_t)(b * K_POST + p);
        #pragma unroll
        for (int j = 0; j < 7; ++j) out[ro * 7 + j] = ob[j];
        out[(size_t)BB * K_POST * 7 + ro] = lb;   // labels (as float values)
        out[(size_t)BB * K_POST * 8 + ro] = sc;   // scores
        out[(size_t)BB * K_POST * 9 + ro] = vd;   // valid (0/1)
    }
}

extern "C" void kernel_launch(void* const* d_in, const int* in_sizes, int n_in,
                              void* d_out, int out_size, void* d_ws, size_t ws_size,
                              hipStream_t stream) {
    const float* boxp = (const float*)d_in[0];
    const float* cls  = (const float*)d_in[1];
    const float* dirp = (const float*)d_in[2];
    const float* anch = (const float*)d_in[3];
    float* out = (float*)d_out;

    char* p = (char*)d_ws;
    u32* key  = (u32*)p; p += (size_t)BB * NN * 4;
    u32* bh   = (u32*)p; p += (size_t)BB * SB * 256 * 4;   // coarse hist slices
    u32* bh2  = (u32*)p; p += (size_t)BB * SB * 256 * 4;   // fine hist slices
    u32* prm  = (u32*)p; p += 256;
    u32* cnt  = (u32*)p; p += 256;
    u32* thr  = (u32*)p; p += 256;
    u64* cand = (u64*)p; p += (size_t)BB * CAP * 8;
    u32* tki  = (u32*)p; p += (size_t)BB * K_PRE * 4;
    float* tks = (float*)p; p += (size_t)BB * K_PRE * 4;
    u32* meta = (u32*)p; p += (size_t)BB * K_PRE * 4;
    float* box7 = (float*)p; p += (size_t)BB * K_PRE * 7 * 4;
    float* cor  = (float*)p; p += (size_t)BB * K_PRE * 5 * 4;
    u64* mask = (u64*)p; p += (size_t)BB * K_PRE * NW * 8;

    hipMemsetAsync(cnt, 0, 256, stream);

    k_score_hist<<<BB * SB, 256, 0, stream>>>(cls, key, bh);
    k_thresh1<<<BB, 256, 0, stream>>>(bh, prm);
    k_hist2<<<BB * SB, 256, 0, stream>>>(key, prm, bh2);
    k_thresh2<<<BB, 256, 0, stream>>>(bh2, prm, thr);
    k_compact<<<(BB * NN) / 256, 256, 0, stream>>>(key, thr, cnt, cand);
    k_sort<<<BB, 1024, 0, stream>>>(cnt, cand, tki);
    k_decode<<<(BB * K_PRE + 255) / 256, 256, 0, stream>>>(boxp, cls, dirp, anch, tki, tks, meta, box7, cor);
    k_mask<<<(BB * K_PRE * NW + 255) / 256, 256, 0, stream>>>(cor, mask);
    k_nms_out<<<BB, 256, 0, stream>>>(meta, box7, tks, mask, out);
}

// Round 5
// 196.829 us; speedup vs baseline: 3.9437x; 1.3967x over previous
//
#include <hip/hip_runtime.h>
#include <stdint.h>

typedef unsigned long long u64;
typedef unsigned int u32;

#define BB 4
#define NN 321408
#define K_PRE 1000
#define K_POST 300
#define CAP 4096
#define NW 16                 // 1000 bits -> 16 u64 words
#define SCORE_THR 0.05f
#define IOU_THR 0.5f
#define SB 314                // slice blocks per batch (ceil(NN/1024))
#define CH2 1024              // anchors per slice block

__device__ __forceinline__ float sigm(float x) { return 1.0f / (1.0f + expf(-x)); }

__device__ __forceinline__ u32 mkkey(float mx) {
    float s = sigm(mx);
    return (s >= SCORE_THR) ? (__float_as_uint(s) | 0x80000000u) : 0u;
}

// ---------------- K1: keys + coarse 256-bin LDS hist -> slices (no global atomics) ----------------
__global__ void k_score_hist(const float* __restrict__ cls, u32* __restrict__ key, u32* __restrict__ bh) {
    __shared__ u32 h[256];
    int bb = blockIdx.x, tid = threadIdx.x;       // grid = BB*SB
    int b = bb / SB, c = bb % SB;
    h[tid] = 0;
    __syncthreads();
    int a0 = c * CH2 + tid * 4;                   // NN % 4 == 0: full quads only
    if (a0 < NN) {
        const float4* c4 = (const float4*)(cls + ((size_t)b * NN + a0) * 3);
        float4 v0 = c4[0], v1 = c4[1], v2 = c4[2];
        uint4 o;
        o.x = mkkey(fmaxf(v0.x, fmaxf(v0.y, v0.z)));
        o.y = mkkey(fmaxf(v0.w, fmaxf(v1.x, v1.y)));
        o.z = mkkey(fmaxf(v1.z, fmaxf(v1.w, v2.x)));
        o.w = mkkey(fmaxf(v2.y, fmaxf(v2.z, v2.w)));
        *((uint4*)(key + (size_t)b * NN + a0)) = o;
        if (o.x) atomicAdd(&h[o.x >> 24], 1u);    // LDS atomics only
        if (o.y) atomicAdd(&h[o.y >> 24], 1u);
        if (o.z) atomicAdd(&h[o.z >> 24], 1u);
        if (o.w) atomicAdd(&h[o.w >> 24], 1u);
    }
    __syncthreads();
    bh[(size_t)bb * 256 + tid] = h[tid];          // coalesced slice write
}

// ---------------- K2a: coarse threshold bin per batch (reduce slices) ----------------
__global__ void k_thresh1(const u32* __restrict__ bh, u32* __restrict__ prm) {
    __shared__ u32 cs[256];
    int b = blockIdx.x, tid = threadIdx.x;        // grid=BB, block=256
    u32 s = 0;
    const u32* base = bh + (size_t)b * SB * 256;
    for (int c = 0; c < SB; ++c) s += base[c * 256 + tid];
    cs[tid] = s;
    __syncthreads();
    if (tid == 0) {
        u32 tot = 0;
        for (int i = 0; i < 256; ++i) tot += cs[i];
        u32 target = (tot < K_PRE) ? tot : K_PRE;
        u32 above = 0; u32 C = 255;
        if (target > 0) {
            u32 acc = 0;
            for (int i = 255; i >= 0; --i) {
                if (acc + cs[i] >= target) { C = (u32)i; above = acc; break; }
                acc += cs[i];
            }
        }
        prm[b * 4 + 0] = C; prm[b * 4 + 1] = target; prm[b * 4 + 2] = above;
    }
}

// ---------------- K2b: fine hist inside coarse bin C -> LDS + slices (no global atomics) ----------------
__global__ void k_hist2(const u32* __restrict__ key, const u32* __restrict__ prm, u32* __restrict__ bh2) {
    __shared__ u32 h[256];
    int bb = blockIdx.x, tid = threadIdx.x;       // grid = BB*SB
    int b = bb / SB, c = bb % SB;
    u32 C = prm[b * 4 + 0], target = prm[b * 4 + 1];
    h[tid] = 0;
    __syncthreads();
    int a0 = c * CH2 + tid * 4;
    if (target != 0 && a0 < NN) {
        uint4 kk = *((const uint4*)(key + (size_t)b * NN + a0));
        if ((kk.x >> 24) == C) atomicAdd(&h[(kk.x >> 16) & 0xFF], 1u);
        if ((kk.y >> 24) == C) atomicAdd(&h[(kk.y >> 16) & 0xFF], 1u);
        if ((kk.z >> 24) == C) atomicAdd(&h[(kk.z >> 16) & 0xFF], 1u);
        if ((kk.w >> 24) == C) atomicAdd(&h[(kk.w >> 16) & 0xFF], 1u);
    }
    __syncthreads();
    bh2[(size_t)bb * 256 + tid] = h[tid];
}

// ---------------- K2c: final 16-bit-bin threshold (reduce slices) ----------------
__global__ void k_thresh2(const u32* __restrict__ bh2, const u32* __restrict__ prm, u32* __restrict__ thr) {
    __shared__ u32 fs[256];
    int b = blockIdx.x, tid = threadIdx.x;        // grid=BB, block=256
    u32 s = 0;
    const u32* base = bh2 + (size_t)b * SB * 256;
    for (int c = 0; c < SB; ++c) s += base[c * 256 + tid];
    fs[tid] = s;
    __syncthreads();
    if (tid == 0) {
        u32 C = prm[b * 4 + 0], target = prm[b * 4 + 1], above = prm[b * 4 + 2];
        if (target == 0) { thr[b] = 0x10000u; }
        else {
            u32 acc = above; u32 T = 0;
            for (int i = 255; i >= 0; --i) {
                acc += fs[i];
                if (acc >= target) { T = (u32)i; break; }
            }
            thr[b] = (C << 8) | T;
        }
    }
}

// ---------------- K3: compact candidates ----------------
__global__ void k_compact(const u32* __restrict__ key, const u32* __restrict__ thr,
                          u32* __restrict__ cnt, u64* __restrict__ cand) {
    int t = blockIdx.x * 256 + threadIdx.x;
    int b = t / NN;
    u32 n = (u32)(t - b * NN);
    u32 k = key[t];
    u32 T = thr[b];
    bool isc = (k != 0) && ((k >> 16) >= T);
    u64 bal = __ballot(isc);
    if (bal) {
        int lane = threadIdx.x & 63;
        int leader = __ffsll(bal) - 1;
        u32 basepos = 0;
        if (lane == leader) basepos = atomicAdd(&cnt[b], (u32)__popcll(bal));
        basepos = __shfl(basepos, leader);
        if (isc) {
            u32 off = basepos + (u32)__popcll(bal & ((1ull << lane) - 1ull));
            // ascending sort of ((~key)<<32)|idx == (score desc, idx asc) == jax top_k order
            if (off < CAP) cand[(size_t)b * CAP + off] = ((u64)(~k) << 32) | (u64)n;
        }
    }
}

// ---------------- K4: bitonic sort candidates, emit top-1000 indices ----------------
__global__ __launch_bounds__(1024) void k_sort(const u32* __restrict__ cnt, const u64* __restrict__ cand,
                                               u32* __restrict__ tki) {
    __shared__ u64 a[CAP];                        // 32 KB
    int b = blockIdx.x; int tid = threadIdx.x;
    u32 nc = cnt[b]; if (nc > CAP) nc = CAP;
    for (int i = tid; i < CAP; i += 1024) a[i] = (i < (int)nc) ? cand[(size_t)b * CAP + i] : ~0ull;
    for (u32 size = 2; size <= CAP; size <<= 1) {
        for (u32 stride = size >> 1; stride > 0; stride >>= 1) {
            __syncthreads();
            for (u32 t = tid; t < CAP / 2; t += 1024) {
                u32 lo = 2 * t - (t & (stride - 1));
                u32 hi = lo + stride;
                bool asc = ((lo & size) == 0);
                u64 x = a[lo], y = a[hi];
                bool sw = asc ? (x > y) : (x < y);
                if (sw) { a[lo] = y; a[hi] = x; }
            }
        }
    }
    __syncthreads();
    for (int i = tid; i < K_PRE; i += 1024) {
        u64 e = a[i];
        u32 kk = ~((u32)(e >> 32));
        tki[b * K_PRE + i] = (kk == 0) ? 0xFFFFFFFFu : (u32)e;
    }
}

// ---------------- K5: decode survivors ----------------
__global__ void k_decode(const float* __restrict__ boxp, const float* __restrict__ cls,
                         const float* __restrict__ dirp, const float* __restrict__ anch,
                         const u32* __restrict__ tki, float* __restrict__ tks, u32* __restrict__ meta,
                         float* __restrict__ box7, float* __restrict__ cor) {
    int t = blockIdx.x * 256 + threadIdx.x;
    if (t >= BB * K_PRE) return;
    int b = t / K_PRE;
    u32 idx = tki[t];
    float ob[7] = {0,0,0,0,0,0,0};
    float c5[5] = {0,0,0,0,0};
    float sc = 0.f; u32 mt = 0;
    if (idx != 0xFFFFFFFFu) {
        const float* A = anch + (size_t)idx * 7;
        const float* D = boxp + ((size_t)b * NN + idx) * 7;
        float xa=A[0], ya=A[1], za=A[2], wa=A[3], la=A[4], ha=A[5], ra=A[6];
        float xt=D[0], yt=D[1], zt=D[2], wt=D[3], lt=D[4], ht=D[5], rt=D[6];
        za = za + ha * 0.5f;
        float diag = sqrtf(la * la + wa * wa);
        float xg = xt * diag + xa;
        float yg = yt * diag + ya;
        float zg = zt * ha + za;
        float wg = expf(wt) * wa;
        float lg = expf(lt) * la;
        float hg = expf(ht) * ha;
        zg = zg - hg * 0.5f;
        float rg = rt + ra;
        ob[0]=xg; ob[1]=yg; ob[2]=zg; ob[3]=wg; ob[4]=lg; ob[5]=hg; ob[6]=rg;
        float cr = fabsf(cosf(rg)), sr = fabsf(sinf(rg));
        float hx = 0.5f * (wg * cr + lg * sr);
        float hy = 0.5f * (wg * sr + lg * cr);
        float x1 = xg - hx, x2 = xg + hx, y1 = yg - hy, y2 = yg + hy;
        c5[0]=x1; c5[1]=x2; c5[2]=y1; c5[3]=y2; c5[4]=(x2-x1)*(y2-y1);
        const float* cc = cls + ((size_t)b * NN + idx) * 3;
        float p0 = sigm(cc[0]), p1 = sigm(cc[1]), p2 = sigm(cc[2]);
        int lbl = 0; float best = p0;
        if (p1 > best) { best = p1; lbl = 1; }
        if (p2 > best) { best = p2; lbl = 2; }
        sc = best;
        const float* dd = dirp + ((size_t)b * NN + idx) * 2;
        int dl = (dd[1] > dd[0]) ? 1 : 0;
        mt = (u32)lbl | ((u32)dl << 8) | (1u << 16);
    }
    tks[t] = sc; meta[t] = mt;
    #pragma unroll
    for (int j = 0; j < 7; ++j) box7[(size_t)t * 7 + j] = ob[j];
    #pragma unroll
    for (int j = 0; j < 5; ++j) cor[(size_t)t * 5 + j] = c5[j];
}

// ---------------- K6: TRANSPOSED suppression bitmask (LDS-staged boxes) ----------------
// maskT[j][w] bit ii: box i=w*64+ii suppresses j (i<j && iou>thr)
__global__ __launch_bounds__(256) void k_maskT(const float* __restrict__ cor, u64* __restrict__ maskT) {
    __shared__ float s4[(K_PRE + 16) * 4];        // x1,x2,y1,y2; index i+(i>>6) breaks bank conflicts
    __shared__ float sA[K_PRE + 16];              // area
    int blk = blockIdx.x;                         // grid = BB * 63
    int b = blk / 63, jb = blk % 63;
    int tid = threadIdx.x;
    const float4* C4 = (const float4*)(cor + (size_t)b * K_PRE * 5);
    for (int q = tid; q < (K_PRE * 5) / 4; q += 256) {
        float4 v = C4[q];
        int t0 = q * 4;
        #pragma unroll
        for (int e = 0; e < 4; ++e) {
            int t = t0 + e;
            int i = t / 5, k = t - i * 5;
            float val = (e == 0) ? v.x : (e == 1) ? v.y : (e == 2) ? v.z : v.w;
            int ip = i + (i >> 6);
            if (k < 4) s4[ip * 4 + k] = val; else sA[ip] = val;
        }
    }
    __syncthreads();
    int w = tid & 15, jl = tid >> 4;
    int j = jb * 16 + jl;
    if (j >= K_PRE) return;
    int jp = j + (j >> 6);
    float x1 = s4[jp*4+0], x2 = s4[jp*4+1], y1 = s4[jp*4+2], y2 = s4[jp*4+3], ar = sA[jp];
    u64 m = 0;
    int i0 = w * 64;
    if (i0 < j) {
        int iend = j - i0; if (iend > 64) iend = 64;
        for (int ii = 0; ii < iend; ++ii) {
            int i = i0 + ii;
            int ip = i + (i >> 6);
            float4 bx = *(const float4*)&s4[ip * 4];
            float ai = sA[ip];
            float ix = fminf(x2, bx.y) - fmaxf(x1, bx.x); ix = fmaxf(ix, 0.f);
            float iy = fminf(y2, bx.w) - fmaxf(y1, bx.z); iy = fmaxf(iy, 0.f);
            float inter = ix * iy;
            float uni = ai + ar - inter;              // fp-add commutative == ref order
            float iou = (uni > 0.f) ? inter / fmaxf(uni, 1e-12f) : 0.f;
            if (iou > IOU_THR) m |= (1ull << ii);
        }
    }
    maskT[((size_t)b * K_PRE + j) * NW + w] = m;
}

// ---------------- K7: greedy NMS, register-serial over KEPT boxes only ----------------
__global__ __launch_bounds__(256) void k_nms_out(const u32* __restrict__ meta, const float* __restrict__ box7,
                                                 const float* __restrict__ tks, const u64* __restrict__ maskT,
                                                 float* __restrict__ out) {
    int b = blockIdx.x; int tid = threadIdx.x;
    __shared__ u64 km_s[16];                      // kept-bits per chunk
    __shared__ int sel_s[K_POST];
    __shared__ int cnt_s;
    if (tid < 16) km_s[tid] = 0ull;
    __syncthreads();
    if (tid < 64) {
        int lane = tid;
        const u32* M = meta + b * K_PRE;
        int cnt = 0; bool done = false;
        for (int c = 0; c < 16; ++c) {            // 16 chunks of 64 candidates
            if (done) break;
            int j = c * 64 + lane;
            int jc = (j < K_PRE) ? j : (K_PRE - 1);
            bool jvalid = (j < K_PRE) && ((M[jc] >> 16) & 1u);
            const u64* colp = maskT + ((size_t)b * K_PRE + jc) * NW;
            u64 cw = 0; u64 supacc = 0;
            #pragma unroll
            for (int w = 0; w < 16; ++w) {        // static indices; km_s[w]=0 for w>=c
                u64 cv = colp[w];
                supacc |= (cv & km_s[w]);
                if (w == c) cw = cv;
            }
            u64 active = __ballot(jvalid && (supacc == 0ull));
            u64 kmc = 0;
            while (active) {
                int i = __ffsll((unsigned long long)active) - 1;   // next kept
                if (lane == 0) sel_s[cnt] = c * 64 + i;
                ++cnt;
                if (cnt >= K_POST) { done = true; break; }
                kmc |= (1ull << i);
                u64 supb = __ballot(((cw >> i) & 1ull) != 0ull);   // i suppresses my j?
                active &= ~supb;
                active &= ~(1ull << i);
            }
            if (lane == 0) km_s[c] = kmc;
        }
        if (lane == 0) cnt_s = cnt;
    }
    __syncthreads();
    int cnt = cnt_s;
    const u32* M = meta + b * K_PRE;
    const float* BX = box7 + (size_t)b * K_PRE * 7;
    const float* SS = tks + b * K_PRE;
    for (int p = tid; p < K_POST; p += 256) {
        float ob[7] = {0,0,0,0,0,0,0};
        float sc = 0.f, lb = 0.f, vd = 0.f;
        if (p < cnt) {
            int i = sel_s[p];
            float xg = BX[i*7+0], yg = BX[i*7+1], zg = BX[i*7+2];
            bool in_range = (xg >= 0.0f) && (xg <= 69.12f) &&
                            (yg >= -39.68f) && (yg <= 39.68f) &&
                            (zg >= -5.0f) && (zg <= 5.0f);
            if (in_range) {
                u32 mt = M[i];
                int dl = (mt >> 8) & 0xFF;
                float r = BX[i*7+6];
                bool opp = ((r > 0.0f) != (dl == 1));
                float rf = r + (opp ? 3.14159274f : 0.0f);
                ob[0]=xg; ob[1]=yg; ob[2]=zg; ob[3]=BX[i*7+3]; ob[4]=BX[i*7+4]; ob[5]=BX[i*7+5]; ob[6]=rf;
                sc = SS[i]; lb = (float)(mt & 0xFF); vd = 1.0f;
            }
        }
        size_t ro = (size_t)(b * K_POST + p);
        #pragma unroll
        for (int j = 0; j < 7; ++j) out[ro * 7 + j] = ob[j];
        out[(size_t)BB * K_POST * 7 + ro] = lb;   // labels (as float values)
        out[(size_t)BB * K_POST * 8 + ro] = sc;   // scores
        out[(size_t)BB * K_POST * 9 + ro] = vd;   // valid (0/1)
    }
}

extern "C" void kernel_launch(void* const* d_in, const int* in_sizes, int n_in,
                              void* d_out, int out_size, void* d_ws, size_t ws_size,
                              hipStream_t stream) {
    const float* boxp = (const float*)d_in[0];
    const float* cls  = (const float*)d_in[1];
    const float* dirp = (const float*)d_in[2];
    const float* anch = (const float*)d_in[3];
    float* out = (float*)d_out;

    char* p = (char*)d_ws;
    u32* key  = (u32*)p; p += (size_t)BB * NN * 4;
    u32* bh   = (u32*)p; p += (size_t)BB * SB * 256 * 4;   // coarse hist slices
    u32* bh2  = (u32*)p; p += (size_t)BB * SB * 256 * 4;   // fine hist slices
    u32* prm  = (u32*)p; p += 256;
    u32* cnt  = (u32*)p; p += 256;
    u32* thr  = (u32*)p; p += 256;
    u64* cand = (u64*)p; p += (size_t)BB * CAP * 8;
    u32* tki  = (u32*)p; p += (size_t)BB * K_PRE * 4;
    float* tks = (float*)p; p += (size_t)BB * K_PRE * 4;
    u32* meta = (u32*)p; p += (size_t)BB * K_PRE * 4;
    float* box7 = (float*)p; p += (size_t)BB * K_PRE * 7 * 4;
    float* cor  = (float*)p; p += (size_t)BB * K_PRE * 5 * 4;
    u64* maskT = (u64*)p; p += (size_t)BB * K_PRE * NW * 8;

    hipMemsetAsync(cnt, 0, 256, stream);

    k_score_hist<<<BB * SB, 256, 0, stream>>>(cls, key, bh);
    k_thresh1<<<BB, 256, 0, stream>>>(bh, prm);
    k_hist2<<<BB * SB, 256, 0, stream>>>(key, prm, bh2);
    k_thresh2<<<BB, 256, 0, stream>>>(bh2, prm, thr);
    k_compact<<<(BB * NN) / 256, 256, 0, stream>>>(key, thr, cnt, cand);
    k_sort<<<BB, 1024, 0, stream>>>(cnt, cand, tki);
    k_decode<<<(BB * K_PRE + 255) / 256, 256, 0, stream>>>(boxp, cls, dirp, anch, tki, tks, meta, box7, cor);
    k_maskT<<<BB * 63, 256, 0, stream>>>(cor, maskT);
    k_nms_out<<<BB, 256, 0, stream>>>(meta, box7, tks, maskT, out);
}

// Round 6
// 146.975 us; speedup vs baseline: 5.2814x; 1.3392x over previous
//
#include <hip/hip_runtime.h>
#include <stdint.h>

typedef unsigned long long u64;
typedef unsigned int u32;

#define BB 4
#define NN 321408
#define K_PRE 1000
#define K_POST 300
#define CAP 4096
#define NW 16                 // 1000 bits -> 16 u64 words
#define SCORE_THR 0.05f
#define IOU_THR 0.5f
#define SB 314                // slice blocks per batch (ceil(NN/1024))
#define CH2 1024              // anchors per slice block

__device__ __forceinline__ float sigm(float x) { return 1.0f / (1.0f + expf(-x)); }

__device__ __forceinline__ u32 mkkey(float mx) {
    float s = sigm(mx);
    return (s >= SCORE_THR) ? (__float_as_uint(s) | 0x80000000u) : 0u;
}

// ---------------- K1: keys + coarse 256-bin LDS hist -> slices (no global atomics) ----------------
__global__ void k_score_hist(const float* __restrict__ cls, u32* __restrict__ key, u32* __restrict__ bh) {
    __shared__ u32 h[256];
    int bb = blockIdx.x, tid = threadIdx.x;       // grid = BB*SB
    int b = bb / SB, c = bb % SB;
    h[tid] = 0;
    __syncthreads();
    int a0 = c * CH2 + tid * 4;                   // NN % 4 == 0: full quads only
    if (a0 < NN) {
        const float4* c4 = (const float4*)(cls + ((size_t)b * NN + a0) * 3);
        float4 v0 = c4[0], v1 = c4[1], v2 = c4[2];
        uint4 o;
        o.x = mkkey(fmaxf(v0.x, fmaxf(v0.y, v0.z)));
        o.y = mkkey(fmaxf(v0.w, fmaxf(v1.x, v1.y)));
        o.z = mkkey(fmaxf(v1.z, fmaxf(v1.w, v2.x)));
        o.w = mkkey(fmaxf(v2.y, fmaxf(v2.z, v2.w)));
        *((uint4*)(key + (size_t)b * NN + a0)) = o;
        if (o.x) atomicAdd(&h[o.x >> 24], 1u);    // LDS atomics only
        if (o.y) atomicAdd(&h[o.y >> 24], 1u);
        if (o.z) atomicAdd(&h[o.z >> 24], 1u);
        if (o.w) atomicAdd(&h[o.w >> 24], 1u);
    }
    __syncthreads();
    bh[(size_t)bb * 256 + tid] = h[tid];          // coalesced slice write
}

// ---------------- K2a: coarse threshold bin per batch (reduce slices) ----------------
__global__ void k_thresh1(const u32* __restrict__ bh, u32* __restrict__ prm) {
    __shared__ u32 cs[256];
    int b = blockIdx.x, tid = threadIdx.x;        // grid=BB, block=256
    u32 s = 0;
    const u32* base = bh + (size_t)b * SB * 256;
    for (int c = 0; c < SB; ++c) s += base[c * 256 + tid];
    cs[tid] = s;
    __syncthreads();
    if (tid == 0) {
        u32 tot = 0;
        for (int i = 0; i < 256; ++i) tot += cs[i];
        u32 target = (tot < K_PRE) ? tot : K_PRE;
        u32 above = 0; u32 C = 255;
        if (target > 0) {
            u32 acc = 0;
            for (int i = 255; i >= 0; --i) {
                if (acc + cs[i] >= target) { C = (u32)i; above = acc; break; }
                acc += cs[i];
            }
        }
        prm[b * 4 + 0] = C; prm[b * 4 + 1] = target; prm[b * 4 + 2] = above;
    }
}

// ---------------- K2b: fine hist inside coarse bin C -> LDS + slices (no global atomics) ----------------
__global__ void k_hist2(const u32* __restrict__ key, const u32* __restrict__ prm, u32* __restrict__ bh2) {
    __shared__ u32 h[256];
    int bb = blockIdx.x, tid = threadIdx.x;       // grid = BB*SB
    int b = bb / SB, c = bb % SB;
    u32 C = prm[b * 4 + 0], target = prm[b * 4 + 1];
    h[tid] = 0;
    __syncthreads();
    int a0 = c * CH2 + tid * 4;
    if (target != 0 && a0 < NN) {
        uint4 kk = *((const uint4*)(key + (size_t)b * NN + a0));
        if ((kk.x >> 24) == C) atomicAdd(&h[(kk.x >> 16) & 0xFF], 1u);
        if ((kk.y >> 24) == C) atomicAdd(&h[(kk.y >> 16) & 0xFF], 1u);
        if ((kk.z >> 24) == C) atomicAdd(&h[(kk.z >> 16) & 0xFF], 1u);
        if ((kk.w >> 24) == C) atomicAdd(&h[(kk.w >> 16) & 0xFF], 1u);
    }
    __syncthreads();
    bh2[(size_t)bb * 256 + tid] = h[tid];
}

// ---------------- K2c: final 16-bit-bin threshold (reduce slices) ----------------
__global__ void k_thresh2(const u32* __restrict__ bh2, const u32* __restrict__ prm, u32* __restrict__ thr) {
    __shared__ u32 fs[256];
    int b = blockIdx.x, tid = threadIdx.x;        // grid=BB, block=256
    u32 s = 0;
    const u32* base = bh2 + (size_t)b * SB * 256;
    for (int c = 0; c < SB; ++c) s += base[c * 256 + tid];
    fs[tid] = s;
    __syncthreads();
    if (tid == 0) {
        u32 C = prm[b * 4 + 0], target = prm[b * 4 + 1], above = prm[b * 4 + 2];
        if (target == 0) { thr[b] = 0x10000u; }
        else {
            u32 acc = above; u32 T = 0;
            for (int i = 255; i >= 0; --i) {
                acc += fs[i];
                if (acc >= target) { T = (u32)i; break; }
            }
            thr[b] = (C << 8) | T;
        }
    }
}

// ---------------- K3a: per-slice candidate count (no atomics) ----------------
__global__ void k_cnt(const u32* __restrict__ key, const u32* __restrict__ thr, u32* __restrict__ bcnt) {
    __shared__ u32 r[4];
    int bb = blockIdx.x, tid = threadIdx.x;       // grid = BB*SB
    int b = bb / SB, c = bb % SB;
    u32 T = thr[b];
    int a0 = c * CH2 + tid * 4;
    u32 tc = 0;
    if (a0 < NN) {
        uint4 kk = *((const uint4*)(key + (size_t)b * NN + a0));
        tc = (u32)((kk.x != 0) && ((kk.x >> 16) >= T)) + (u32)((kk.y != 0) && ((kk.y >> 16) >= T))
           + (u32)((kk.z != 0) && ((kk.z >> 16) >= T)) + (u32)((kk.w != 0) && ((kk.w >> 16) >= T));
    }
    u32 v = tc;
    #pragma unroll
    for (int o = 32; o > 0; o >>= 1) v += __shfl_down(v, o);
    if ((tid & 63) == 0) r[tid >> 6] = v;
    __syncthreads();
    if (tid == 0) bcnt[bb] = r[0] + r[1] + r[2] + r[3];
}

// ---------------- K3b: per-batch exclusive prefix over slice counts ----------------
__global__ __launch_bounds__(512) void k_scan(const u32* __restrict__ bcnt, u32* __restrict__ boff,
                                              u32* __restrict__ cnt) {
    __shared__ u32 s[512];
    int b = blockIdx.x, tid = threadIdx.x;        // grid=BB, block=512 (SB=314 <= 512)
    u32 v = (tid < SB) ? bcnt[b * SB + tid] : 0u;
    s[tid] = v;
    __syncthreads();
    for (int o = 1; o < 512; o <<= 1) {
        u32 x = (tid >= o) ? s[tid - o] : 0u;
        __syncthreads();
        s[tid] += x;
        __syncthreads();
    }
    if (tid < SB) boff[b * SB + tid] = s[tid] - v;  // exclusive prefix
    if (tid == 511) cnt[b] = s[511];                // batch total
}

// ---------------- K3c: scatter candidates at prefix offsets (no atomics) ----------------
__global__ void k_scatter(const u32* __restrict__ key, const u32* __restrict__ thr,
                          const u32* __restrict__ boff, u64* __restrict__ cand) {
    __shared__ u32 s[256];
    int bb = blockIdx.x, tid = threadIdx.x;       // grid = BB*SB
    int b = bb / SB, c = bb % SB;
    u32 T = thr[b];
    int a0 = c * CH2 + tid * 4;
    uint4 kk = make_uint4(0u, 0u, 0u, 0u);
    if (a0 < NN) kk = *((const uint4*)(key + (size_t)b * NN + a0));
    u32 ks[4] = {kk.x, kk.y, kk.z, kk.w};
    u32 f[4];
    #pragma unroll
    for (int e = 0; e < 4; ++e) f[e] = (u32)((ks[e] != 0) && ((ks[e] >> 16) >= T));
    u32 tc = f[0] + f[1] + f[2] + f[3];
    s[tid] = tc;
    __syncthreads();
    for (int o = 1; o < 256; o <<= 1) {
        u32 x = (tid >= o) ? s[tid - o] : 0u;
        __syncthreads();
        s[tid] += x;
        __syncthreads();
    }
    u32 pos = boff[bb] + s[tid] - tc;
    u64* cb = cand + (size_t)b * CAP;
    #pragma unroll
    for (int e = 0; e < 4; ++e) {
        if (f[e]) {
            // ascending sort of ((~key)<<32)|idx == (score desc, idx asc) == jax top_k order
            if (pos < CAP) cb[pos] = ((u64)(~ks[e]) << 32) | (u64)(a0 + e);
            ++pos;
        }
    }
}

// ---------------- K4: bitonic sort candidates, emit top-1000 indices ----------------
__global__ __launch_bounds__(1024) void k_sort(const u32* __restrict__ cnt, const u64* __restrict__ cand,
                                               u32* __restrict__ tki) {
    __shared__ u64 a[CAP];                        // 32 KB
    int b = blockIdx.x; int tid = threadIdx.x;
    u32 nc = cnt[b]; if (nc > CAP) nc = CAP;
    for (int i = tid; i < CAP; i += 1024) a[i] = (i < (int)nc) ? cand[(size_t)b * CAP + i] : ~0ull;
    for (u32 size = 2; size <= CAP; size <<= 1) {
        for (u32 stride = size >> 1; stride > 0; stride >>= 1) {
            __syncthreads();
            for (u32 t = tid; t < CAP / 2; t += 1024) {
                u32 lo = 2 * t - (t & (stride - 1));
                u32 hi = lo + stride;
                bool asc = ((lo & size) == 0);
                u64 x = a[lo], y = a[hi];
                bool sw = asc ? (x > y) : (x < y);
                if (sw) { a[lo] = y; a[hi] = x; }
            }
        }
    }
    __syncthreads();
    for (int i = tid; i < K_PRE; i += 1024) {
        u64 e = a[i];
        u32 kk = ~((u32)(e >> 32));
        tki[b * K_PRE + i] = (kk == 0) ? 0xFFFFFFFFu : (u32)e;
    }
}

// ---------------- K5: decode survivors ----------------
__global__ void k_decode(const float* __restrict__ boxp, const float* __restrict__ cls,
                         const float* __restrict__ dirp, const float* __restrict__ anch,
                         const u32* __restrict__ tki, float* __restrict__ tks, u32* __restrict__ meta,
                         float* __restrict__ box7, float* __restrict__ cor) {
    int t = blockIdx.x * 256 + threadIdx.x;
    if (t >= BB * K_PRE) return;
    int b = t / K_PRE;
    u32 idx = tki[t];
    float ob[7] = {0,0,0,0,0,0,0};
    float c5[5] = {0,0,0,0,0};
    float sc = 0.f; u32 mt = 0;
    if (idx != 0xFFFFFFFFu) {
        const float* A = anch + (size_t)idx * 7;
        const float* D = boxp + ((size_t)b * NN + idx) * 7;
        float xa=A[0], ya=A[1], za=A[2], wa=A[3], la=A[4], ha=A[5], ra=A[6];
        float xt=D[0], yt=D[1], zt=D[2], wt=D[3], lt=D[4], ht=D[5], rt=D[6];
        za = za + ha * 0.5f;
        float diag = sqrtf(la * la + wa * wa);
        float xg = xt * diag + xa;
        float yg = yt * diag + ya;
        float zg = zt * ha + za;
        float wg = expf(wt) * wa;
        float lg = expf(lt) * la;
        float hg = expf(ht) * ha;
        zg = zg - hg * 0.5f;
        float rg = rt + ra;
        ob[0]=xg; ob[1]=yg; ob[2]=zg; ob[3]=wg; ob[4]=lg; ob[5]=hg; ob[6]=rg;
        float cr = fabsf(cosf(rg)), sr = fabsf(sinf(rg));
        float hx = 0.5f * (wg * cr + lg * sr);
        float hy = 0.5f * (wg * sr + lg * cr);
        float x1 = xg - hx, x2 = xg + hx, y1 = yg - hy, y2 = yg + hy;
        c5[0]=x1; c5[1]=x2; c5[2]=y1; c5[3]=y2; c5[4]=(x2-x1)*(y2-y1);
        const float* cc = cls + ((size_t)b * NN + idx) * 3;
        float p0 = sigm(cc[0]), p1 = sigm(cc[1]), p2 = sigm(cc[2]);
        int lbl = 0; float best = p0;
        if (p1 > best) { best = p1; lbl = 1; }
        if (p2 > best) { best = p2; lbl = 2; }
        sc = best;
        const float* dd = dirp + ((size_t)b * NN + idx) * 2;
        int dl = (dd[1] > dd[0]) ? 1 : 0;
        mt = (u32)lbl | ((u32)dl << 8) | (1u << 16);
    }
    tks[t] = sc; meta[t] = mt;
    #pragma unroll
    for (int j = 0; j < 7; ++j) box7[(size_t)t * 7 + j] = ob[j];
    #pragma unroll
    for (int j = 0; j < 5; ++j) cor[(size_t)t * 5 + j] = c5[j];
}

// ---------------- K6: TRANSPOSED suppression bitmask (LDS-staged boxes) ----------------
// maskT[j][w] bit ii: box i=w*64+ii suppresses j (i<j && iou>thr)
__global__ __launch_bounds__(256) void k_maskT(const float* __restrict__ cor, u64* __restrict__ maskT) {
    __shared__ float s4[(K_PRE + 16) * 4];        // x1,x2,y1,y2; index i+(i>>6) breaks bank conflicts
    __shared__ float sA[K_PRE + 16];              // area
    int blk = blockIdx.x;                         // grid = BB * 63
    int b = blk / 63, jb = blk % 63;
    int tid = threadIdx.x;
    const float4* C4 = (const float4*)(cor + (size_t)b * K_PRE * 5);
    for (int q = tid; q < (K_PRE * 5) / 4; q += 256) {
        float4 v = C4[q];
        int t0 = q * 4;
        #pragma unroll
        for (int e = 0; e < 4; ++e) {
            int t = t0 + e;
            int i = t / 5, k = t - i * 5;
            float val = (e == 0) ? v.x : (e == 1) ? v.y : (e == 2) ? v.z : v.w;
            int ip = i + (i >> 6);
            if (k < 4) s4[ip * 4 + k] = val; else sA[ip] = val;
        }
    }
    __syncthreads();
    int w = tid & 15, jl = tid >> 4;
    int j = jb * 16 + jl;
    if (j >= K_PRE) return;
    int jp = j + (j >> 6);
    float x1 = s4[jp*4+0], x2 = s4[jp*4+1], y1 = s4[jp*4+2], y2 = s4[jp*4+3], ar = sA[jp];
    u64 m = 0;
    int i0 = w * 64;
    if (i0 < j) {
        int iend = j - i0; if (iend > 64) iend = 64;
        for (int ii = 0; ii < iend; ++ii) {
            int i = i0 + ii;
            int ip = i + (i >> 6);
            float4 bx = *(const float4*)&s4[ip * 4];
            float ai = sA[ip];
            float ix = fminf(x2, bx.y) - fmaxf(x1, bx.x); ix = fmaxf(ix, 0.f);
            float iy = fminf(y2, bx.w) - fmaxf(y1, bx.z); iy = fmaxf(iy, 0.f);
            float inter = ix * iy;
            float uni = ai + ar - inter;              // fp-add commutative == ref order
            float iou = (uni > 0.f) ? inter / fmaxf(uni, 1e-12f) : 0.f;
            if (iou > IOU_THR) m |= (1ull << ii);
        }
    }
    maskT[((size_t)b * K_PRE + j) * NW + w] = m;
}

// ---------------- K7: greedy NMS, register-serial over KEPT boxes only ----------------
__global__ __launch_bounds__(256) void k_nms_out(const u32* __restrict__ meta, const float* __restrict__ box7,
                                                 const float* __restrict__ tks, const u64* __restrict__ maskT,
                                                 float* __restrict__ out) {
    int b = blockIdx.x; int tid = threadIdx.x;
    __shared__ u64 km_s[16];                      // kept-bits per chunk
    __shared__ int sel_s[K_POST];
    __shared__ int cnt_s;
    if (tid < 16) km_s[tid] = 0ull;
    __syncthreads();
    if (tid < 64) {
        int lane = tid;
        const u32* M = meta + b * K_PRE;
        int cnt = 0; bool done = false;
        for (int c = 0; c < 16; ++c) {            // 16 chunks of 64 candidates
            if (done) break;
            int j = c * 64 + lane;
            int jc = (j < K_PRE) ? j : (K_PRE - 1);
            bool jvalid = (j < K_PRE) && ((M[jc] >> 16) & 1u);
            const u64* colp = maskT + ((size_t)b * K_PRE + jc) * NW;
            u64 cw = 0; u64 supacc = 0;
            #pragma unroll
            for (int w = 0; w < 16; ++w) {        // static indices; km_s[w]=0 for w>=c
                u64 cv = colp[w];
                supacc |= (cv & km_s[w]);
                if (w == c) cw = cv;
            }
            u64 active = __ballot(jvalid && (supacc == 0ull));
            u64 kmc = 0;
            while (active) {
                int i = __ffsll((unsigned long long)active) - 1;   // next kept
                if (lane == 0) sel_s[cnt] = c * 64 + i;
                ++cnt;
                if (cnt >= K_POST) { done = true; break; }
                kmc |= (1ull << i);
                u64 supb = __ballot(((cw >> i) & 1ull) != 0ull);   // i suppresses my j?
                active &= ~supb;
                active &= ~(1ull << i);
            }
            if (lane == 0) km_s[c] = kmc;
        }
        if (lane == 0) cnt_s = cnt;
    }
    __syncthreads();
    int cnt = cnt_s;
    const u32* M = meta + b * K_PRE;
    const float* BX = box7 + (size_t)b * K_PRE * 7;
    const float* SS = tks + b * K_PRE;
    for (int p = tid; p < K_POST; p += 256) {
        float ob[7] = {0,0,0,0,0,0,0};
        float sc = 0.f, lb = 0.f, vd = 0.f;
        if (p < cnt) {
            int i = sel_s[p];
            float xg = BX[i*7+0], yg = BX[i*7+1], zg = BX[i*7+2];
            bool in_range = (xg >= 0.0f) && (xg <= 69.12f) &&
                            (yg >= -39.68f) && (yg <= 39.68f) &&
                            (zg >= -5.0f) && (zg <= 5.0f);
            if (in_range) {
                u32 mt = M[i];
                int dl = (mt >> 8) & 0xFF;
                float r = BX[i*7+6];
                bool opp = ((r > 0.0f) != (dl == 1));
                float rf = r + (opp ? 3.14159274f : 0.0f);
                ob[0]=xg; ob[1]=yg; ob[2]=zg; ob[3]=BX[i*7+3]; ob[4]=BX[i*7+4]; ob[5]=BX[i*7+5]; ob[6]=rf;
                sc = SS[i]; lb = (float)(mt & 0xFF); vd = 1.0f;
            }
        }
        size_t ro = (size_t)(b * K_POST + p);
        #pragma unroll
        for (int j = 0; j < 7; ++j) out[ro * 7 + j] = ob[j];
        out[(size_t)BB * K_POST * 7 + ro] = lb;   // labels (as float values)
        out[(size_t)BB * K_POST * 8 + ro] = sc;   // scores
        out[(size_t)BB * K_POST * 9 + ro] = vd;   // valid (0/1)
    }
}

extern "C" void kernel_launch(void* const* d_in, const int* in_sizes, int n_in,
                              void* d_out, int out_size, void* d_ws, size_t ws_size,
                              hipStream_t stream) {
    const float* boxp = (const float*)d_in[0];
    const float* cls  = (const float*)d_in[1];
    const float* dirp = (const float*)d_in[2];
    const float* anch = (const float*)d_in[3];
    float* out = (float*)d_out;

    char* p = (char*)d_ws;
    u32* key  = (u32*)p; p += (size_t)BB * NN * 4;
    u32* bh   = (u32*)p; p += (size_t)BB * SB * 256 * 4;   // coarse hist slices
    u32* bh2  = (u32*)p; p += (size_t)BB * SB * 256 * 4;   // fine hist slices
    u32* prm  = (u32*)p; p += 256;
    u32* cnt  = (u32*)p; p += 256;
    u32* thr  = (u32*)p; p += 256;
    u32* bcnt = (u32*)p; p += (size_t)BB * SB * 4 + 256;
    u32* boff = (u32*)p; p += (size_t)BB * SB * 4 + 256;
    u64* cand = (u64*)p; p += (size_t)BB * CAP * 8;
    u32* tki  = (u32*)p; p += (size_t)BB * K_PRE * 4;
    float* tks = (float*)p; p += (size_t)BB * K_PRE * 4;
    u32* meta = (u32*)p; p += (size_t)BB * K_PRE * 4;
    float* box7 = (float*)p; p += (size_t)BB * K_PRE * 7 * 4;
    float* cor  = (float*)p; p += (size_t)BB * K_PRE * 5 * 4;
    u64* maskT = (u64*)p; p += (size_t)BB * K_PRE * NW * 8;

    k_score_hist<<<BB * SB, 256, 0, stream>>>(cls, key, bh);
    k_thresh1<<<BB, 256, 0, stream>>>(bh, prm);
    k_hist2<<<BB * SB, 256, 0, stream>>>(key, prm, bh2);
    k_thresh2<<<BB, 256, 0, stream>>>(bh2, prm, thr);
    k_cnt<<<BB * SB, 256, 0, stream>>>(key, thr, bcnt);
    k_scan<<<BB, 512, 0, stream>>>(bcnt, boff, cnt);
    k_scatter<<<BB * SB, 256, 0, stream>>>(key, thr, boff, cand);
    k_sort<<<BB, 1024, 0, stream>>>(cnt, cand, tki);
    k_decode<<<(BB * K_PRE + 255) / 256, 256, 0, stream>>>(boxp, cls, dirp, anch, tki, tks, meta, box7, cor);
    k_maskT<<<BB * 63, 256, 0, stream>>>(cor, maskT);
    k_nms_out<<<BB, 256, 0, stream>>>(meta, box7, tks, maskT, out);
}